// Round 4
// baseline (1127.178 us; speedup 1.0000x reference)
//
#include <hip/hip_runtime.h>
#include <hip/hip_bf16.h>
#include <math.h>

// Outputs are FLOAT32 (reference returns f32/int32; harness reads one flat f32 buffer).
// B=8, L=1024, K=30, F=128 -> flat offsets (f32 elements):
//   V    [0,        1048576)
//   E    [1048576,  32505856)
//   Eidx [32505856, 32751616)
//   bb   [32751616, 32882688)
#define V_OFF    ((size_t)0)
#define E_OFF    ((size_t)1048576)
#define EIDX_OFF ((size_t)32505856)
#define BB_OFF   ((size_t)32751616)

#define K 30
#define NRBF 16
#define NGROUP 25
#define EDGE_IN 400

// atom indices: N=0, Ca=1, C=2, CB=3, O=4
__device__ __constant__ int c_pairA[24] = {0,2,4,3,1,1,1,1,0,0,0,3,3,4,0,2,4,3,2,4,3,2,4,2};
__device__ __constant__ int c_pairB[24] = {0,2,4,3,0,2,4,3,2,4,3,2,4,2,1,1,1,1,0,0,0,3,3,4};

__device__ __forceinline__ void norm_to(const float v[3], float o[3]) {
    float n = sqrtf(v[0]*v[0] + v[1]*v[1] + v[2]*v[2]);
    n = fmaxf(n, 1e-12f);
    o[0] = v[0]/n; o[1] = v[1]/n; o[2] = v[2]/n;
}
__device__ __forceinline__ void unit_diff(const float a[3], const float b[3], float o[3]) {
    float v[3] = {a[0]-b[0], a[1]-b[1], a[2]-b[2]};
    norm_to(v, o);
}
__device__ __forceinline__ void cross_unit(const float a[3], const float b[3], float o[3]) {
    float c[3] = {a[1]*b[2]-a[2]*b[1], a[2]*b[0]-a[0]*b[2], a[0]*b[1]-a[1]*b[0]};
    norm_to(c, o);
}

// ---------------- kernel 1: node features (V) + backbone frames (bb) ----------------
__global__ __launch_bounds__(128) void node_bb_kernel(
    const float* __restrict__ X, const float* __restrict__ Wn,
    const float* __restrict__ gn, const float* __restrict__ bn,
    float* __restrict__ out)
{
    const int blk = blockIdx.x;
    const int b = blk >> 10, i = blk & 1023;
    const int tid = threadIdx.x;
    __shared__ float ang[3];
    __shared__ float red[128];

    if (tid < 3) {
        const int m = 3*i + tid;
        float dang = 0.f;
        if (m >= 1 && m <= 3*1024 - 3) {
            const int t = m - 1;
            float P[4][3];
            #pragma unroll
            for (int q = 0; q < 4; ++q) {
                const int s = t + q;
                const int ri = s / 3, ai = s - 3*ri;
                const float* p = X + (((size_t)b * 1024 + ri) * 5 + ai) * 3;
                P[q][0] = p[0]; P[q][1] = p[1]; P[q][2] = p[2];
            }
            float u2v[3], u1v[3], u0v[3];
            unit_diff(P[1], P[0], u2v);
            unit_diff(P[2], P[1], u1v);
            unit_diff(P[3], P[2], u0v);
            float n2v[3], n1v[3];
            cross_unit(u2v, u1v, n2v);
            cross_unit(u1v, u0v, n1v);
            float cosD = n2v[0]*n1v[0] + n2v[1]*n1v[1] + n2v[2]*n1v[2];
            cosD = fminf(fmaxf(cosD, -1.f + 1e-7f), 1.f - 1e-7f);
            float sg = u2v[0]*n1v[0] + u2v[1]*n1v[1] + u2v[2]*n1v[2];
            float s = (sg > 0.f) ? 1.f : ((sg < 0.f) ? -1.f : 0.f);
            dang = s * acosf(cosD);
        }
        ang[tid] = dang;
    }
    if (tid == 3) {
        const float* p = X + (size_t)blk * 15;
        float Nx=p[0],  Ny=p[1],  Nz=p[2];
        float Cax=p[3], Cay=p[4], Caz=p[5];
        float Cx=p[6],  Cy=p[7],  Cz=p[8];
        float v1[3] = {Cx-Cax, Cy-Cay, Cz-Caz};
        float v2[3] = {Nx-Cax, Ny-Cay, Nz-Caz};
        float e1[3]; norm_to(v1, e1);
        float dd = e1[0]*v2[0] + e1[1]*v2[1] + e1[2]*v2[2];
        float u2[3] = {v2[0]-e1[0]*dd, v2[1]-e1[1]*dd, v2[2]-e1[2]*dd};
        float e2[3]; norm_to(u2, e2);
        float e3[3] = {e1[1]*e2[2]-e1[2]*e2[1], e1[2]*e2[0]-e1[0]*e2[2], e1[0]*e2[1]-e1[1]*e2[0]};
        float* bb = out + BB_OFF + (size_t)blk * 16;
        bb[0]=e1[0]; bb[1]=e1[1]; bb[2]=e1[2];  bb[3]=Cax;
        bb[4]=e2[0]; bb[5]=e2[1]; bb[6]=e2[2];  bb[7]=Cay;
        bb[8]=e3[0]; bb[9]=e3[1]; bb[10]=e3[2]; bb[11]=Caz;
        bb[12]=0.f; bb[13]=0.f; bb[14]=0.f; bb[15]=0.f;
    }
    __syncthreads();
    const float a0 = ang[0], a1 = ang[1], a2 = ang[2];
    float feat[6] = {cosf(a0), cosf(a1), cosf(a2), sinf(a0), sinf(a1), sinf(a2)};
    float x = 0.f;
    #pragma unroll
    for (int f = 0; f < 6; ++f) x += feat[f] * Wn[f*128 + tid];
    red[tid] = x; __syncthreads();
    for (int s = 64; s > 0; s >>= 1) { if (tid < s) red[tid] += red[tid+s]; __syncthreads(); }
    const float mean = red[0] * (1.f/128.f);
    __syncthreads();
    const float xm = x - mean;
    red[tid] = xm*xm; __syncthreads();
    for (int s = 64; s > 0; s >>= 1) { if (tid < s) red[tid] += red[tid+s]; __syncthreads(); }
    const float var = red[0] * (1.f/128.f);
    const float y = xm / __fsqrt_rn(var + 1e-5f) * gn[tid] + bn[tid];
    out[V_OFF + (size_t)blk * 128 + tid] = y;
}

// ---------------- kernel 2: fused top-k + edge features ----------------
__global__ __launch_bounds__(256) void topk_edge_kernel(
    const float* __restrict__ X, const float* __restrict__ mask,
    const float* __restrict__ We, const float* __restrict__ Wp,
    const float* __restrict__ bp, const float* __restrict__ ge,
    const float* __restrict__ be, float* __restrict__ out)
{
    const int blk = blockIdx.x;
    const int b = blk >> 10, i = blk & 1023;
    const int tid = threadIdx.x;

    __shared__ float smem[K * EDGE_IN];          // phase1: smem[0..1023]=m2 ; phase2: rbf / S
    __shared__ float Dadj[1024];
    __shared__ float redf[256];
    __shared__ unsigned long long redk[256];
    __shared__ float nbA[K][15];
    __shared__ int   nj[K];
    __shared__ float dnbv[K];

    // ---- phase 1: masked distances + stable top-k (all in LDS) ----
    const float* Xb = X + (size_t)b * 15360;     // L*15 floats per batch
    const float cix = Xb[i*15 + 3];
    const float ciy = Xb[i*15 + 4];
    const float ciz = Xb[i*15 + 5];
    const float mi  = mask[(b << 10) + i];

    float lmax = -1.f;
    for (int j = tid; j < 1024; j += 256) {
        const float dx = __fsub_rn(cix, Xb[j*15 + 3]);
        const float dy = __fsub_rn(ciy, Xb[j*15 + 4]);
        const float dz = __fsub_rn(ciz, Xb[j*15 + 5]);
        // numpy association order: ((dx^2+dy^2)+dz^2)+1e-6
        const float ss = __fadd_rn(__fadd_rn(__fmul_rn(dx,dx), __fmul_rn(dy,dy)), __fmul_rn(dz,dz));
        const float dist = __fsqrt_rn(__fadd_rn(ss, 1e-6f));
        const float m2 = __fmul_rn(mi, mask[(b << 10) + j]);
        const float Dv = __fmul_rn(m2, dist);
        Dadj[j] = Dv; smem[j] = m2;
        lmax = fmaxf(lmax, Dv);
    }
    redf[tid] = lmax; __syncthreads();
    for (int s = 128; s > 0; s >>= 1) { if (tid < s) redf[tid] = fmaxf(redf[tid], redf[tid+s]); __syncthreads(); }
    const float Dmax = redf[0];
    __syncthreads();
    for (int j = tid; j < 1024; j += 256)
        Dadj[j] = __fadd_rn(Dadj[j], __fmul_rn(__fsub_rn(1.f, smem[j]), Dmax));
    __syncthreads();

    for (int k = 0; k < K; ++k) {
        unsigned long long best = ~0ull;
        for (int j = tid; j < 1024; j += 256) {
            unsigned long long key = ((unsigned long long)__float_as_uint(Dadj[j]) << 32) | (unsigned)j;
            best = key < best ? key : best;
        }
        redk[tid] = best; __syncthreads();
        for (int s = 128; s > 0; s >>= 1) {
            if (tid < s) { unsigned long long o = redk[tid+s]; if (o < redk[tid]) redk[tid] = o; }
            __syncthreads();
        }
        if (tid == 0) {
            const unsigned long long kk = redk[0];
            const int j = (int)(kk & 0xffffffffu);
            nj[k] = j;
            dnbv[k] = __uint_as_float((unsigned)(kk >> 32));
            out[EIDX_OFF + (size_t)blk * K + k] = (float)j;
            Dadj[j] = __int_as_float(0x7f800000);   // +inf: remove from pool
        }
        __syncthreads();
    }

    // ---- phase 2: edge features ----
    for (int t = tid; t < K*15; t += 256) {
        const int e = t / 15, r = t - e*15;
        nbA[e][r] = X[((size_t)(b << 10) + nj[e])*15 + r];
    }
    __syncthreads();   // also guards smem reuse (m2 dead from here)

    const float* sa = X + (size_t)blk * 15;
    for (int t = tid; t < K*NGROUP; t += 256) {
        const int e = t / NGROUP, g = t - e*NGROUP;
        float d;
        if (g == 0) d = dnbv[e];
        else {
            const int p = g - 1;
            const int aA = c_pairA[p], aB = c_pairB[p];
            const float dx = sa[aA*3+0] - nbA[e][aB*3+0];
            const float dy = sa[aA*3+1] - nbA[e][aB*3+1];
            const float dz = sa[aA*3+2] - nbA[e][aB*3+2];
            d = sqrtf(dx*dx + dy*dy + dz*dz + 1e-6f);
        }
        float* rp = &smem[e*EDGE_IN + g*NRBF];
        #pragma unroll
        for (int k = 0; k < NRBF; ++k) {
            const float mu = 2.f + k * (4.f/3.f);
            const float z = (d - mu) * 0.8f;     // /sigma, sigma=1.25
            rp[k] = __expf(-z*z);
        }
    }
    __syncthreads();

    // (30 x 400) @ (400 x 128), f-dim split across block halves
    const int j = tid & 127;
    const int h = tid >> 7;
    float acc[K];
    #pragma unroll
    for (int e = 0; e < K; ++e) acc[e] = 0.f;
    const float* Wcol = We + j;
    for (int f0 = h*200; f0 < h*200 + 200; f0 += 4) {
        const float w0 = Wcol[(f0+0)*128];
        const float w1 = Wcol[(f0+1)*128];
        const float w2 = Wcol[(f0+2)*128];
        const float w3 = Wcol[(f0+3)*128];
        #pragma unroll
        for (int e = 0; e < K; ++e) {
            const float4 r4 = *reinterpret_cast<const float4*>(&smem[e*EDGE_IN + f0]);
            acc[e] = fmaf(r4.x, w0, fmaf(r4.y, w1, fmaf(r4.z, w2, fmaf(r4.w, w3, acc[e]))));
        }
    }
    __syncthreads();               // all rbf reads done; reuse smem as S[e*128+j]
    float* S = smem;
    if (h == 1) { for (int e = 0; e < K; ++e) S[e*128 + j] = acc[e]; }
    __syncthreads();
    if (h == 0) {
        for (int e = 0; e < K; ++e) {
            float v = acc[e] + S[e*128 + j];
            int off = i - nj[e] + 32;
            off = off < 0 ? 0 : (off > 64 ? 64 : off);
            v += Wp[off*128 + j] + bp[j];
            S[e*128 + j] = v;
        }
    }
    __syncthreads();

    // per-edge LayerNorm, one wave per edge round-robin
    const int wave = tid >> 6, lane = tid & 63;
    const float inv128 = 1.f/128.f;
    for (int e = wave; e < K; e += 4) {
        const float x0 = S[e*128 + lane], x1 = S[e*128 + lane + 64];
        float sum = x0 + x1;
        #pragma unroll
        for (int s = 32; s > 0; s >>= 1) sum += __shfl_xor(sum, s);
        const float mean = sum * inv128;
        const float d0 = x0 - mean, d1 = x1 - mean;
        float vs = d0*d0 + d1*d1;
        #pragma unroll
        for (int s = 32; s > 0; s >>= 1) vs += __shfl_xor(vs, s);
        const float inv = 1.f / __fsqrt_rn(vs * inv128 + 1e-5f);
        const size_t base = E_OFF + ((size_t)blk * K + e) * 128;
        out[base + lane]      = d0 * inv * ge[lane]      + be[lane];
        out[base + lane + 64] = d1 * inv * ge[lane + 64] + be[lane + 64];
    }
}

extern "C" void kernel_launch(void* const* d_in, const int* in_sizes, int n_in,
                              void* d_out, int out_size, void* d_ws, size_t ws_size,
                              hipStream_t stream) {
    const float* X    = (const float*)d_in[0];
    const float* mask = (const float*)d_in[1];
    // d_in[2] = Lvec (int32), unused
    const float* We   = (const float*)d_in[3];
    const float* Wn   = (const float*)d_in[4];
    const float* Wp   = (const float*)d_in[5];
    const float* bp   = (const float*)d_in[6];
    const float* gE   = (const float*)d_in[7];
    const float* bE   = (const float*)d_in[8];
    const float* gN   = (const float*)d_in[9];
    const float* bN   = (const float*)d_in[10];
    float* out = (float*)d_out;

    hipLaunchKernelGGL(node_bb_kernel,   dim3(8192), dim3(128), 0, stream, X, Wn, gN, bN, out);
    hipLaunchKernelGGL(topk_edge_kernel, dim3(8192), dim3(256), 0, stream,
                       X, mask, We, Wp, bp, gE, bE, out);
}

// Round 5
// 461.152 us; speedup vs baseline: 2.4443x; 2.4443x over previous
//
#include <hip/hip_runtime.h>
#include <hip/hip_bf16.h>
#include <math.h>

// Outputs are FLOAT32. B=8, L=1024, K=30, F=128 -> flat offsets (f32 elements):
#define V_OFF    ((size_t)0)
#define E_OFF    ((size_t)1048576)
#define EIDX_OFF ((size_t)32505856)
#define BB_OFF   ((size_t)32751616)

#define K 30
#define NRBF 16
#define NGROUP 25
#define KPAD 416          // 13 * 32
#define AROW 424          // padded LDS row stride (bf16 elems) for bank spread
#define SSTR 132          // padded S stride (f32)

typedef __attribute__((ext_vector_type(8))) short bf16x8;
typedef __attribute__((ext_vector_type(4))) float f32x4;

// atom indices: N=0, Ca=1, C=2, CB=3, O=4
__device__ __constant__ int c_pairA[24] = {0,2,4,3,1,1,1,1,0,0,0,3,3,4,0,2,4,3,2,4,3,2,4,2};
__device__ __constant__ int c_pairB[24] = {0,2,4,3,0,2,4,3,2,4,3,2,4,2,1,1,1,1,0,0,0,3,3,4};

__device__ __forceinline__ unsigned short f2bu(float f) {   // RNE f32->bf16 bits (finite)
    unsigned x = __float_as_uint(f);
    return (unsigned short)((x + 0x7fffu + ((x >> 16) & 1u)) >> 16);
}

__device__ __forceinline__ void norm_to(const float v[3], float o[3]) {
    float n = sqrtf(v[0]*v[0] + v[1]*v[1] + v[2]*v[2]);
    n = fmaxf(n, 1e-12f);
    o[0] = v[0]/n; o[1] = v[1]/n; o[2] = v[2]/n;
}
__device__ __forceinline__ void unit_diff(const float a[3], const float b[3], float o[3]) {
    float v[3] = {a[0]-b[0], a[1]-b[1], a[2]-b[2]};
    norm_to(v, o);
}
__device__ __forceinline__ void cross_unit(const float a[3], const float b[3], float o[3]) {
    float c[3] = {a[1]*b[2]-a[2]*b[1], a[2]*b[0]-a[0]*b[2], a[0]*b[1]-a[1]*b[0]};
    norm_to(c, o);
}

// ---------------- kernel 0: We (400x128 f32) -> Wb fragment-major bf16 in ws ----------------
// Wb[(s*128 + j)*32 + kk] = bf16(We[(s*32+kk)*128 + j]), zero-padded for k>=400.
__global__ __launch_bounds__(128) void wb_prep_kernel(
    const float* __restrict__ We, unsigned short* __restrict__ Wb)
{
    const int s = blockIdx.x;          // 0..12
    const int j = threadIdx.x;         // 0..127
    unsigned* dst = (unsigned*)(Wb + ((size_t)(s*128 + j) << 5));
    #pragma unroll
    for (int m = 0; m < 16; ++m) {
        const int k0 = s*32 + 2*m;
        const unsigned lo = (k0   < 400) ? f2bu(We[(size_t)k0*128 + j])     : 0u;
        const unsigned hi = (k0+1 < 400) ? f2bu(We[(size_t)(k0+1)*128 + j]) : 0u;
        dst[m] = (hi << 16) | lo;
    }
}

// ---------------- kernel 1: node features (V) + backbone frames (bb) ----------------
__global__ __launch_bounds__(128) void node_bb_kernel(
    const float* __restrict__ X, const float* __restrict__ Wn,
    const float* __restrict__ gn, const float* __restrict__ bn,
    float* __restrict__ out)
{
    const int blk = blockIdx.x;
    const int b = blk >> 10, i = blk & 1023;
    const int tid = threadIdx.x;
    __shared__ float ang[3];
    __shared__ float red[128];

    if (tid < 3) {
        const int m = 3*i + tid;
        float dang = 0.f;
        if (m >= 1 && m <= 3*1024 - 3) {
            const int t = m - 1;
            float P[4][3];
            #pragma unroll
            for (int q = 0; q < 4; ++q) {
                const int s = t + q;
                const int ri = s / 3, ai = s - 3*ri;
                const float* p = X + (((size_t)b * 1024 + ri) * 5 + ai) * 3;
                P[q][0] = p[0]; P[q][1] = p[1]; P[q][2] = p[2];
            }
            float u2v[3], u1v[3], u0v[3];
            unit_diff(P[1], P[0], u2v);
            unit_diff(P[2], P[1], u1v);
            unit_diff(P[3], P[2], u0v);
            float n2v[3], n1v[3];
            cross_unit(u2v, u1v, n2v);
            cross_unit(u1v, u0v, n1v);
            float cosD = n2v[0]*n1v[0] + n2v[1]*n1v[1] + n2v[2]*n1v[2];
            cosD = fminf(fmaxf(cosD, -1.f + 1e-7f), 1.f - 1e-7f);
            float sg = u2v[0]*n1v[0] + u2v[1]*n1v[1] + u2v[2]*n1v[2];
            float s = (sg > 0.f) ? 1.f : ((sg < 0.f) ? -1.f : 0.f);
            dang = s * acosf(cosD);
        }
        ang[tid] = dang;
    }
    if (tid == 3) {
        const float* p = X + (size_t)blk * 15;
        float Nx=p[0],  Ny=p[1],  Nz=p[2];
        float Cax=p[3], Cay=p[4], Caz=p[5];
        float Cx=p[6],  Cy=p[7],  Cz=p[8];
        float v1[3] = {Cx-Cax, Cy-Cay, Cz-Caz};
        float v2[3] = {Nx-Cax, Ny-Cay, Nz-Caz};
        float e1[3]; norm_to(v1, e1);
        float dd = e1[0]*v2[0] + e1[1]*v2[1] + e1[2]*v2[2];
        float u2[3] = {v2[0]-e1[0]*dd, v2[1]-e1[1]*dd, v2[2]-e1[2]*dd};
        float e2[3]; norm_to(u2, e2);
        float e3[3] = {e1[1]*e2[2]-e1[2]*e2[1], e1[2]*e2[0]-e1[0]*e2[2], e1[0]*e2[1]-e1[1]*e2[0]};
        float* bb = out + BB_OFF + (size_t)blk * 16;
        bb[0]=e1[0]; bb[1]=e1[1]; bb[2]=e1[2];  bb[3]=Cax;
        bb[4]=e2[0]; bb[5]=e2[1]; bb[6]=e2[2];  bb[7]=Cay;
        bb[8]=e3[0]; bb[9]=e3[1]; bb[10]=e3[2]; bb[11]=Caz;
        bb[12]=0.f; bb[13]=0.f; bb[14]=0.f; bb[15]=0.f;
    }
    __syncthreads();
    const float a0 = ang[0], a1 = ang[1], a2 = ang[2];
    float feat[6] = {cosf(a0), cosf(a1), cosf(a2), sinf(a0), sinf(a1), sinf(a2)};
    float x = 0.f;
    #pragma unroll
    for (int f = 0; f < 6; ++f) x += feat[f] * Wn[f*128 + tid];
    red[tid] = x; __syncthreads();
    for (int s = 64; s > 0; s >>= 1) { if (tid < s) red[tid] += red[tid+s]; __syncthreads(); }
    const float mean = red[0] * (1.f/128.f);
    __syncthreads();
    const float xm = x - mean;
    red[tid] = xm*xm; __syncthreads();
    for (int s = 64; s > 0; s >>= 1) { if (tid < s) red[tid] += red[tid+s]; __syncthreads(); }
    const float var = red[0] * (1.f/128.f);
    const float y = xm / __fsqrt_rn(var + 1e-5f) * gn[tid] + bn[tid];
    out[V_OFF + (size_t)blk * 128 + tid] = y;
}

// ---------------- kernel 2: fused top-k + edge features (MFMA phase B) ----------------
__global__ __launch_bounds__(256) void topk_edge_kernel(
    const float* __restrict__ X, const float* __restrict__ mask,
    const unsigned short* __restrict__ Wb, const float* __restrict__ Wp,
    const float* __restrict__ bp, const float* __restrict__ ge,
    const float* __restrict__ be, float* __restrict__ out)
{
    const int blk = blockIdx.x;
    const int b = blk >> 10, i = blk & 1023;
    const int tid = threadIdx.x;

    __shared__ unsigned short A_lds[32 * AROW];   // 27136 B: bf16 rbf tile (phase 2)
    __shared__ float S[K * SSTR];                  // 15840 B
    __shared__ float redf[256];
    __shared__ unsigned long long redk[256];
    __shared__ float nbA[K][15];
    __shared__ int   nj[K];
    __shared__ float dnbv[K];

    // ---- phase 1: masked distances + stable top-k (candidates in registers) ----
    const float* Xb = X + (size_t)b * 15360;
    const float cix = Xb[i*15 + 3];
    const float ciy = Xb[i*15 + 4];
    const float ciz = Xb[i*15 + 5];
    const float mi  = mask[(b << 10) + i];

    float dv_r[4], m2_r[4];
    float lmax = -1.f;
    #pragma unroll
    for (int m = 0; m < 4; ++m) {
        const int j = tid + (m << 8);
        const float dx = __fsub_rn(cix, Xb[j*15 + 3]);
        const float dy = __fsub_rn(ciy, Xb[j*15 + 4]);
        const float dz = __fsub_rn(ciz, Xb[j*15 + 5]);
        const float ss = __fadd_rn(__fadd_rn(__fmul_rn(dx,dx), __fmul_rn(dy,dy)), __fmul_rn(dz,dz));
        const float dist = __fsqrt_rn(__fadd_rn(ss, 1e-6f));
        const float m2 = __fmul_rn(mi, mask[(b << 10) + j]);
        const float Dv = __fmul_rn(m2, dist);
        dv_r[m] = Dv; m2_r[m] = m2;
        lmax = fmaxf(lmax, Dv);
    }
    redf[tid] = lmax; __syncthreads();
    for (int s = 128; s > 0; s >>= 1) { if (tid < s) redf[tid] = fmaxf(redf[tid], redf[tid+s]); __syncthreads(); }
    const float Dmax = redf[0];

    unsigned long long key[4];
    #pragma unroll
    for (int m = 0; m < 4; ++m) {
        const float adj = __fadd_rn(dv_r[m], __fmul_rn(__fsub_rn(1.f, m2_r[m]), Dmax));
        key[m] = ((unsigned long long)__float_as_uint(adj) << 32) | (unsigned)(tid + (m << 8));
    }
    __syncthreads();

    for (int k = 0; k < K; ++k) {
        unsigned long long best = key[0];
        if (key[1] < best) best = key[1];
        if (key[2] < best) best = key[2];
        if (key[3] < best) best = key[3];
        redk[tid] = best; __syncthreads();
        for (int s = 128; s > 0; s >>= 1) {
            if (tid < s) { unsigned long long o = redk[tid+s]; if (o < redk[tid]) redk[tid] = o; }
            __syncthreads();
        }
        const unsigned long long kk = redk[0];
        const int j = (int)(kk & 0xffffffffu);
        if ((j & 255) == tid) key[j >> 8] = ~0ull;   // owner invalidates
        if (tid == 0) {
            nj[k] = j;
            dnbv[k] = __uint_as_float((unsigned)(kk >> 32));
            out[EIDX_OFF + (size_t)blk * K + k] = (float)j;
        }
        __syncthreads();
    }

    // ---- phase 2a: zero A tile + fetch neighbor atoms ----
    {
        unsigned* az = (unsigned*)A_lds;
        for (int t = tid; t < (32*AROW)/2; t += 256) az[t] = 0u;
    }
    for (int t = tid; t < K*15; t += 256) {
        const int e = t / 15, r = t - e*15;
        nbA[e][r] = X[((size_t)(b << 10) + nj[e])*15 + r];
    }
    __syncthreads();

    // ---- phase 2b: rbf -> bf16 A tile ----
    const float* sa = X + (size_t)blk * 15;
    for (int t = tid; t < K*NGROUP; t += 256) {
        const int e = t / NGROUP, g = t - e*NGROUP;
        float d;
        if (g == 0) d = dnbv[e];
        else {
            const int p = g - 1;
            const int aA = c_pairA[p], aB = c_pairB[p];
            const float dx = sa[aA*3+0] - nbA[e][aB*3+0];
            const float dy = sa[aA*3+1] - nbA[e][aB*3+1];
            const float dz = sa[aA*3+2] - nbA[e][aB*3+2];
            d = sqrtf(dx*dx + dy*dy + dz*dz + 1e-6f);
        }
        unsigned* dst = (unsigned*)A_lds + (e*AROW + g*NRBF)/2;
        #pragma unroll
        for (int m = 0; m < 8; ++m) {
            const float mu0 = 2.f + (2*m)   * (4.f/3.f);
            const float mu1 = 2.f + (2*m+1) * (4.f/3.f);
            const float z0 = (d - mu0) * 0.8f;
            const float z1 = (d - mu1) * 0.8f;
            const unsigned lo = f2bu(__expf(-z0*z0));
            const unsigned hi = f2bu(__expf(-z1*z1));
            dst[m] = (hi << 16) | lo;
        }
    }
    __syncthreads();

    // ---- phase 2c: MFMA (32x416) @ (416x128); wave w owns N columns [32w, 32w+32) ----
    {
        const int w = tid >> 6, l = tid & 63;
        const int ar = l & 15;          // A row within tile / B col within tile
        const int kg = (l >> 4) * 8;    // k-offset group
        f32x4 acc00 = {0,0,0,0}, acc01 = {0,0,0,0}, acc10 = {0,0,0,0}, acc11 = {0,0,0,0};
        const unsigned short* a_base = A_lds + ar*AROW + kg;
        const unsigned short* b_base = Wb + ((size_t)(w*32 + ar) << 5) + kg;
        for (int s = 0; s < 13; ++s) {
            const bf16x8 a0 = *reinterpret_cast<const bf16x8*>(a_base + s*32);
            const bf16x8 a1 = *reinterpret_cast<const bf16x8*>(a_base + 16*AROW + s*32);
            const bf16x8 b0 = *reinterpret_cast<const bf16x8*>(b_base + (size_t)s*4096);
            const bf16x8 b1 = *reinterpret_cast<const bf16x8*>(b_base + (size_t)s*4096 + 512);
            acc00 = __builtin_amdgcn_mfma_f32_16x16x32_bf16(a0, b0, acc00, 0, 0, 0);
            acc01 = __builtin_amdgcn_mfma_f32_16x16x32_bf16(a0, b1, acc01, 0, 0, 0);
            acc10 = __builtin_amdgcn_mfma_f32_16x16x32_bf16(a1, b0, acc10, 0, 0, 0);
            acc11 = __builtin_amdgcn_mfma_f32_16x16x32_bf16(a1, b1, acc11, 0, 0, 0);
        }
        // C layout (m89): col = lane&15, row = (lane>>4)*4 + reg
        const int crow = (l >> 4) * 4;
        const int ccol = w*32 + ar;
        #pragma unroll
        for (int r = 0; r < 4; ++r) {
            const int r0 = crow + r;
            if (r0 < K) { S[r0*SSTR + ccol] = acc00[r]; S[r0*SSTR + ccol + 16] = acc01[r]; }
            const int r1 = 16 + crow + r;
            if (r1 < K) { S[r1*SSTR + ccol] = acc10[r]; S[r1*SSTR + ccol + 16] = acc11[r]; }
        }
    }
    __syncthreads();

    // ---- phase 2d: + positional embedding + bias ----
    for (int t = tid; t < K*128; t += 256) {
        const int e = t >> 7, j = t & 127;
        int off = i - nj[e] + 32;
        off = off < 0 ? 0 : (off > 64 ? 64 : off);
        S[e*SSTR + j] += Wp[off*128 + j] + bp[j];
    }
    __syncthreads();

    // ---- phase 2e: per-edge LayerNorm ----
    const int wave = tid >> 6, lane = tid & 63;
    const float inv128 = 1.f/128.f;
    for (int e = wave; e < K; e += 4) {
        const float x0 = S[e*SSTR + lane], x1 = S[e*SSTR + lane + 64];
        float sum = x0 + x1;
        #pragma unroll
        for (int s = 32; s > 0; s >>= 1) sum += __shfl_xor(sum, s);
        const float mean = sum * inv128;
        const float d0 = x0 - mean, d1 = x1 - mean;
        float vs = d0*d0 + d1*d1;
        #pragma unroll
        for (int s = 32; s > 0; s >>= 1) vs += __shfl_xor(vs, s);
        const float inv = 1.f / __fsqrt_rn(vs * inv128 + 1e-5f);
        const size_t base = E_OFF + ((size_t)blk * K + e) * 128;
        out[base + lane]      = d0 * inv * ge[lane]      + be[lane];
        out[base + lane + 64] = d1 * inv * ge[lane + 64] + be[lane + 64];
    }
}

extern "C" void kernel_launch(void* const* d_in, const int* in_sizes, int n_in,
                              void* d_out, int out_size, void* d_ws, size_t ws_size,
                              hipStream_t stream) {
    const float* X    = (const float*)d_in[0];
    const float* mask = (const float*)d_in[1];
    // d_in[2] = Lvec (int32), unused
    const float* We   = (const float*)d_in[3];
    const float* Wn   = (const float*)d_in[4];
    const float* Wp   = (const float*)d_in[5];
    const float* bp   = (const float*)d_in[6];
    const float* gE   = (const float*)d_in[7];
    const float* bE   = (const float*)d_in[8];
    const float* gN   = (const float*)d_in[9];
    const float* bN   = (const float*)d_in[10];
    float* out = (float*)d_out;
    unsigned short* Wb = (unsigned short*)d_ws;   // 13*128*32 bf16 = 106496 B

    hipLaunchKernelGGL(wb_prep_kernel,   dim3(13),   dim3(128), 0, stream, We, Wb);
    hipLaunchKernelGGL(node_bb_kernel,   dim3(8192), dim3(128), 0, stream, X, Wn, gN, bN, out);
    hipLaunchKernelGGL(topk_edge_kernel, dim3(8192), dim3(256), 0, stream,
                       X, mask, Wb, Wp, bp, gE, bE, out);
}

// Round 6
// 281.641 us; speedup vs baseline: 4.0022x; 1.6374x over previous
//
#include <hip/hip_runtime.h>
#include <hip/hip_bf16.h>
#include <math.h>

// Outputs are FLOAT32. B=8, L=1024, K=30, F=128 -> flat offsets (f32 elements):
#define V_OFF    ((size_t)0)
#define E_OFF    ((size_t)1048576)
#define EIDX_OFF ((size_t)32505856)
#define BB_OFF   ((size_t)32751616)

#define K 30
#define NRBF 16
#define NGROUP 25
#define KPAD 416          // 13 * 32
#define AROW 424          // padded LDS row stride (bf16 elems) for bank spread
#define SSTR 132          // padded S stride (f32)

typedef __attribute__((ext_vector_type(8))) short bf16x8;
typedef __attribute__((ext_vector_type(4))) float f32x4;

// atom indices: N=0, Ca=1, C=2, CB=3, O=4
__device__ __constant__ int c_pairA[24] = {0,2,4,3,1,1,1,1,0,0,0,3,3,4,0,2,4,3,2,4,3,2,4,2};
__device__ __constant__ int c_pairB[24] = {0,2,4,3,0,2,4,3,2,4,3,2,4,2,1,1,1,1,0,0,0,3,3,4};

__device__ __forceinline__ unsigned short f2bu(float f) {   // RNE f32->bf16 bits (finite)
    unsigned x = __float_as_uint(f);
    return (unsigned short)((x + 0x7fffu + ((x >> 16) & 1u)) >> 16);
}

__device__ __forceinline__ void norm_to(const float v[3], float o[3]) {
    float n = sqrtf(v[0]*v[0] + v[1]*v[1] + v[2]*v[2]);
    n = fmaxf(n, 1e-12f);
    o[0] = v[0]/n; o[1] = v[1]/n; o[2] = v[2]/n;
}
__device__ __forceinline__ void unit_diff(const float a[3], const float b[3], float o[3]) {
    float v[3] = {a[0]-b[0], a[1]-b[1], a[2]-b[2]};
    norm_to(v, o);
}
__device__ __forceinline__ void cross_unit(const float a[3], const float b[3], float o[3]) {
    float c[3] = {a[1]*b[2]-a[2]*b[1], a[2]*b[0]-a[0]*b[2], a[0]*b[1]-a[1]*b[0]};
    norm_to(c, o);
}

// ---------------- kernel 0: We (400x128 f32) -> Wb fragment-major bf16 in ws ----------------
__global__ __launch_bounds__(128) void wb_prep_kernel(
    const float* __restrict__ We, unsigned short* __restrict__ Wb)
{
    const int s = blockIdx.x;          // 0..12
    const int j = threadIdx.x;         // 0..127
    unsigned* dst = (unsigned*)(Wb + ((size_t)(s*128 + j) << 5));
    #pragma unroll
    for (int m = 0; m < 16; ++m) {
        const int k0 = s*32 + 2*m;
        const unsigned lo = (k0   < 400) ? f2bu(We[(size_t)k0*128 + j])     : 0u;
        const unsigned hi = (k0+1 < 400) ? f2bu(We[(size_t)(k0+1)*128 + j]) : 0u;
        dst[m] = (hi << 16) | lo;
    }
}

// ---------------- kernel 1: node features (V) + backbone frames (bb) ----------------
__global__ __launch_bounds__(128) void node_bb_kernel(
    const float* __restrict__ X, const float* __restrict__ Wn,
    const float* __restrict__ gn, const float* __restrict__ bn,
    float* __restrict__ out)
{
    const int blk = blockIdx.x;
    const int b = blk >> 10, i = blk & 1023;
    const int tid = threadIdx.x;
    __shared__ float ang[3];
    __shared__ float red[128];

    if (tid < 3) {
        const int m = 3*i + tid;
        float dang = 0.f;
        if (m >= 1 && m <= 3*1024 - 3) {
            const int t = m - 1;
            float P[4][3];
            #pragma unroll
            for (int q = 0; q < 4; ++q) {
                const int s = t + q;
                const int ri = s / 3, ai = s - 3*ri;
                const float* p = X + (((size_t)b * 1024 + ri) * 5 + ai) * 3;
                P[q][0] = p[0]; P[q][1] = p[1]; P[q][2] = p[2];
            }
            float u2v[3], u1v[3], u0v[3];
            unit_diff(P[1], P[0], u2v);
            unit_diff(P[2], P[1], u1v);
            unit_diff(P[3], P[2], u0v);
            float n2v[3], n1v[3];
            cross_unit(u2v, u1v, n2v);
            cross_unit(u1v, u0v, n1v);
            float cosD = n2v[0]*n1v[0] + n2v[1]*n1v[1] + n2v[2]*n1v[2];
            cosD = fminf(fmaxf(cosD, -1.f + 1e-7f), 1.f - 1e-7f);
            float sg = u2v[0]*n1v[0] + u2v[1]*n1v[1] + u2v[2]*n1v[2];
            float s = (sg > 0.f) ? 1.f : ((sg < 0.f) ? -1.f : 0.f);
            dang = s * acosf(cosD);
        }
        ang[tid] = dang;
    }
    if (tid == 3) {
        const float* p = X + (size_t)blk * 15;
        float Nx=p[0],  Ny=p[1],  Nz=p[2];
        float Cax=p[3], Cay=p[4], Caz=p[5];
        float Cx=p[6],  Cy=p[7],  Cz=p[8];
        float v1[3] = {Cx-Cax, Cy-Cay, Cz-Caz};
        float v2[3] = {Nx-Cax, Ny-Cay, Nz-Caz};
        float e1[3]; norm_to(v1, e1);
        float dd = e1[0]*v2[0] + e1[1]*v2[1] + e1[2]*v2[2];
        float u2[3] = {v2[0]-e1[0]*dd, v2[1]-e1[1]*dd, v2[2]-e1[2]*dd};
        float e2[3]; norm_to(u2, e2);
        float e3[3] = {e1[1]*e2[2]-e1[2]*e2[1], e1[2]*e2[0]-e1[0]*e2[2], e1[0]*e2[1]-e1[1]*e2[0]};
        float* bb = out + BB_OFF + (size_t)blk * 16;
        bb[0]=e1[0]; bb[1]=e1[1]; bb[2]=e1[2];  bb[3]=Cax;
        bb[4]=e2[0]; bb[5]=e2[1]; bb[6]=e2[2];  bb[7]=Cay;
        bb[8]=e3[0]; bb[9]=e3[1]; bb[10]=e3[2]; bb[11]=Caz;
        bb[12]=0.f; bb[13]=0.f; bb[14]=0.f; bb[15]=0.f;
    }
    __syncthreads();
    const float a0 = ang[0], a1 = ang[1], a2 = ang[2];
    float feat[6] = {cosf(a0), cosf(a1), cosf(a2), sinf(a0), sinf(a1), sinf(a2)};
    float x = 0.f;
    #pragma unroll
    for (int f = 0; f < 6; ++f) x += feat[f] * Wn[f*128 + tid];
    red[tid] = x; __syncthreads();
    for (int s = 64; s > 0; s >>= 1) { if (tid < s) red[tid] += red[tid+s]; __syncthreads(); }
    const float mean = red[0] * (1.f/128.f);
    __syncthreads();
    const float xm = x - mean;
    red[tid] = xm*xm; __syncthreads();
    for (int s = 64; s > 0; s >>= 1) { if (tid < s) red[tid] += red[tid+s]; __syncthreads(); }
    const float var = red[0] * (1.f/128.f);
    const float y = xm / __fsqrt_rn(var + 1e-5f) * gn[tid] + bn[tid];
    out[V_OFF + (size_t)blk * 128 + tid] = y;
}

// ---------------- kernel 2: fused top-k + edge features ----------------
__global__ __launch_bounds__(256) void topk_edge_kernel(
    const float* __restrict__ X, const float* __restrict__ mask,
    const unsigned short* __restrict__ Wb, const float* __restrict__ Wp,
    const float* __restrict__ bp, const float* __restrict__ ge,
    const float* __restrict__ be, float* __restrict__ out)
{
    const int blk = blockIdx.x;
    const int b = blk >> 10, i = blk & 1023;
    const int tid = threadIdx.x;
    const int w = tid >> 6, lane = tid & 63;

    __shared__ __align__(16) unsigned char smem_raw[32 * AROW * 2];  // 27136 B: A tile, later S
    __shared__ unsigned long long wl[4][K];     // per-wave local top-30 lists
    __shared__ float redf4[4];
    __shared__ float nbA[K][15];
    __shared__ int   nj[K];
    __shared__ float dnbv[K];
    unsigned short* A_lds = (unsigned short*)smem_raw;
    float* S = (float*)smem_raw;                 // union; guarded by barriers

    // ---- phase 1: masked distances, keys in registers ----
    const float* Xb = X + (size_t)b * 15360;
    const float cix = Xb[i*15 + 3];
    const float ciy = Xb[i*15 + 4];
    const float ciz = Xb[i*15 + 5];
    const float mi  = mask[(b << 10) + i];

    float dv_r[4], m2_r[4];
    float lmax = -1.f;
    #pragma unroll
    for (int m = 0; m < 4; ++m) {
        const int j = tid + (m << 8);
        const float dx = __fsub_rn(cix, Xb[j*15 + 3]);
        const float dy = __fsub_rn(ciy, Xb[j*15 + 4]);
        const float dz = __fsub_rn(ciz, Xb[j*15 + 5]);
        // numpy association order: ((dx^2+dy^2)+dz^2)+1e-6
        const float ss = __fadd_rn(__fadd_rn(__fmul_rn(dx,dx), __fmul_rn(dy,dy)), __fmul_rn(dz,dz));
        const float dist = __fsqrt_rn(__fadd_rn(ss, 1e-6f));
        const float m2 = __fmul_rn(mi, mask[(b << 10) + j]);
        const float Dv = __fmul_rn(m2, dist);
        dv_r[m] = Dv; m2_r[m] = m2;
        lmax = fmaxf(lmax, Dv);
    }
    #pragma unroll
    for (int s = 1; s < 64; s <<= 1) lmax = fmaxf(lmax, __shfl_xor(lmax, s));
    if (lane == 0) redf4[w] = lmax;
    __syncthreads();
    const float Dmax = fmaxf(fmaxf(redf4[0], redf4[1]), fmaxf(redf4[2], redf4[3]));

    unsigned long long loc0, loc1, loc2, loc3;
    {
        const float a0 = __fadd_rn(dv_r[0], __fmul_rn(__fsub_rn(1.f, m2_r[0]), Dmax));
        const float a1 = __fadd_rn(dv_r[1], __fmul_rn(__fsub_rn(1.f, m2_r[1]), Dmax));
        const float a2 = __fadd_rn(dv_r[2], __fmul_rn(__fsub_rn(1.f, m2_r[2]), Dmax));
        const float a3 = __fadd_rn(dv_r[3], __fmul_rn(__fsub_rn(1.f, m2_r[3]), Dmax));
        loc0 = ((unsigned long long)__float_as_uint(a0) << 32) | (unsigned)(tid);
        loc1 = ((unsigned long long)__float_as_uint(a1) << 32) | (unsigned)(tid + 256);
        loc2 = ((unsigned long long)__float_as_uint(a2) << 32) | (unsigned)(tid + 512);
        loc3 = ((unsigned long long)__float_as_uint(a3) << 32) | (unsigned)(tid + 768);
    }

    // ---- per-wave local top-30 (barrier-free; keys distinct so order is exact) ----
    for (int k = 0; k < K; ++k) {
        unsigned long long best = loc0 < loc1 ? loc0 : loc1;
        const unsigned long long b23 = loc2 < loc3 ? loc2 : loc3;
        best = best < b23 ? best : b23;
        #pragma unroll
        for (int s = 1; s < 64; s <<= 1) {
            const unsigned long long o = __shfl_xor(best, s);
            best = o < best ? o : best;
        }
        if (lane == 0) wl[w][k] = best;
        const unsigned jw = (unsigned)(best & 0xffffffffu);
        if ((jw & 255u) == (unsigned)tid) {
            switch (jw >> 8) {
                case 0: loc0 = ~0ull; break;
                case 1: loc1 = ~0ull; break;
                case 2: loc2 = ~0ull; break;
                default: loc3 = ~0ull; break;
            }
        }
    }
    __syncthreads();

    // ---- 4-way merge of sorted lists (wave 0; lanes redundant, lane 0 writes) ----
    if (w == 0) {
        int h0 = 0, h1 = 0, h2 = 0, h3 = 0;
        for (int k = 0; k < K; ++k) {
            const unsigned long long c0 = wl[0][h0], c1 = wl[1][h1];
            const unsigned long long c2 = wl[2][h2], c3 = wl[3][h3];
            unsigned long long mb = c0 < c1 ? c0 : c1;
            const unsigned long long m23 = c2 < c3 ? c2 : c3;
            mb = mb < m23 ? mb : m23;
            if (lane == 0) {
                const int j = (int)(mb & 0xffffffffu);
                nj[k] = j;
                dnbv[k] = __uint_as_float((unsigned)(mb >> 32));
                out[EIDX_OFF + (size_t)blk * K + k] = (float)j;
            }
            if (mb == c0) ++h0; else if (mb == c1) ++h1; else if (mb == c2) ++h2; else ++h3;
        }
    }
    __syncthreads();

    // ---- phase 2a: zero A pad region + fetch neighbor atoms ----
    {
        unsigned* az = (unsigned*)A_lds;
        // rows 0..31, k in [400,416): 8 u32 per row
        for (int t = tid; t < 32*8; t += 256) { const int r = t >> 3, c = t & 7; az[r*212 + 200 + c] = 0u; }
        // rows 30,31, k in [0,400): 200 u32 per row
        for (int t = tid; t < 400; t += 256) { const int r = 30 + (t >= 200), c = t % 200; az[r*212 + c] = 0u; }
    }
    for (int t = tid; t < K*15; t += 256) {
        const int e = t / 15, r = t - e*15;
        nbA[e][r] = X[((size_t)(b << 10) + nj[e])*15 + r];
    }
    __syncthreads();

    // ---- phase 2b: rbf -> bf16 A tile ----
    const float* sa = X + (size_t)blk * 15;
    for (int t = tid; t < K*NGROUP; t += 256) {
        const int e = t / NGROUP, g = t - e*NGROUP;
        float d;
        if (g == 0) d = dnbv[e];
        else {
            const int p = g - 1;
            const int aA = c_pairA[p], aB = c_pairB[p];
            const float dx = sa[aA*3+0] - nbA[e][aB*3+0];
            const float dy = sa[aA*3+1] - nbA[e][aB*3+1];
            const float dz = sa[aA*3+2] - nbA[e][aB*3+2];
            d = sqrtf(dx*dx + dy*dy + dz*dz + 1e-6f);
        }
        unsigned* dst = (unsigned*)A_lds + (e*AROW + g*NRBF)/2;
        #pragma unroll
        for (int m = 0; m < 8; ++m) {
            const float mu0 = 2.f + (2*m)   * (4.f/3.f);
            const float mu1 = 2.f + (2*m+1) * (4.f/3.f);
            const float z0 = (d - mu0) * 0.8f;
            const float z1 = (d - mu1) * 0.8f;
            const unsigned lo = f2bu(__expf(-z0*z0));
            const unsigned hi = f2bu(__expf(-z1*z1));
            dst[m] = (hi << 16) | lo;
        }
    }
    __syncthreads();

    // ---- phase 2c: MFMA (32x416) @ (416x128); wave w owns N columns [32w, 32w+32) ----
    f32x4 acc00 = {0,0,0,0}, acc01 = {0,0,0,0}, acc10 = {0,0,0,0}, acc11 = {0,0,0,0};
    {
        const int ar = lane & 15;          // A row within tile / B col within tile
        const int kg = (lane >> 4) * 8;    // k-offset group
        const unsigned short* a_base = A_lds + ar*AROW + kg;
        const unsigned short* b_base = Wb + ((size_t)(w*32 + ar) << 5) + kg;
        for (int s = 0; s < 13; ++s) {
            const bf16x8 a0 = *reinterpret_cast<const bf16x8*>(a_base + s*32);
            const bf16x8 a1 = *reinterpret_cast<const bf16x8*>(a_base + 16*AROW + s*32);
            const bf16x8 b0 = *reinterpret_cast<const bf16x8*>(b_base + (size_t)s*4096);
            const bf16x8 b1 = *reinterpret_cast<const bf16x8*>(b_base + (size_t)s*4096 + 512);
            acc00 = __builtin_amdgcn_mfma_f32_16x16x32_bf16(a0, b0, acc00, 0, 0, 0);
            acc01 = __builtin_amdgcn_mfma_f32_16x16x32_bf16(a0, b1, acc01, 0, 0, 0);
            acc10 = __builtin_amdgcn_mfma_f32_16x16x32_bf16(a1, b0, acc10, 0, 0, 0);
            acc11 = __builtin_amdgcn_mfma_f32_16x16x32_bf16(a1, b1, acc11, 0, 0, 0);
        }
    }
    __syncthreads();                       // all A reads complete; smem becomes S
    {
        // C layout (m89): col = lane&15, row = (lane>>4)*4 + reg
        const int crow = (lane >> 4) * 4;
        const int ccol = w*32 + (lane & 15);
        #pragma unroll
        for (int r = 0; r < 4; ++r) {
            const int r0 = crow + r;
            if (r0 < K) { S[r0*SSTR + ccol] = acc00[r]; S[r0*SSTR + ccol + 16] = acc01[r]; }
            const int r1 = 16 + crow + r;
            if (r1 < K) { S[r1*SSTR + ccol] = acc10[r]; S[r1*SSTR + ccol + 16] = acc11[r]; }
        }
    }
    __syncthreads();

    // ---- phase 2d: + positional embedding + bias ----
    for (int t = tid; t < K*128; t += 256) {
        const int e = t >> 7, j = t & 127;
        int off = i - nj[e] + 32;
        off = off < 0 ? 0 : (off > 64 ? 64 : off);
        S[e*SSTR + j] += Wp[off*128 + j] + bp[j];
    }
    __syncthreads();

    // ---- phase 2e: per-edge LayerNorm ----
    const float inv128 = 1.f/128.f;
    for (int e = w; e < K; e += 4) {
        const float x0 = S[e*SSTR + lane], x1 = S[e*SSTR + lane + 64];
        float sum = x0 + x1;
        #pragma unroll
        for (int s = 32; s > 0; s >>= 1) sum += __shfl_xor(sum, s);
        const float mean = sum * inv128;
        const float d0 = x0 - mean, d1 = x1 - mean;
        float vs = d0*d0 + d1*d1;
        #pragma unroll
        for (int s = 32; s > 0; s >>= 1) vs += __shfl_xor(vs, s);
        const float inv = 1.f / __fsqrt_rn(vs * inv128 + 1e-5f);
        const size_t base = E_OFF + ((size_t)blk * K + e) * 128;
        out[base + lane]      = d0 * inv * ge[lane]      + be[lane];
        out[base + lane + 64] = d1 * inv * ge[lane + 64] + be[lane + 64];
    }
}

extern "C" void kernel_launch(void* const* d_in, const int* in_sizes, int n_in,
                              void* d_out, int out_size, void* d_ws, size_t ws_size,
                              hipStream_t stream) {
    const float* X    = (const float*)d_in[0];
    const float* mask = (const float*)d_in[1];
    // d_in[2] = Lvec (int32), unused
    const float* We   = (const float*)d_in[3];
    const float* Wn   = (const float*)d_in[4];
    const float* Wp   = (const float*)d_in[5];
    const float* bp   = (const float*)d_in[6];
    const float* gE   = (const float*)d_in[7];
    const float* bE   = (const float*)d_in[8];
    const float* gN   = (const float*)d_in[9];
    const float* bN   = (const float*)d_in[10];
    float* out = (float*)d_out;
    unsigned short* Wb = (unsigned short*)d_ws;   // 13*128*32 bf16 = 106496 B

    hipLaunchKernelGGL(wb_prep_kernel,   dim3(13),   dim3(128), 0, stream, We, Wb);
    hipLaunchKernelGGL(node_bb_kernel,   dim3(8192), dim3(128), 0, stream, X, Wn, gN, bN, out);
    hipLaunchKernelGGL(topk_edge_kernel, dim3(8192), dim3(256), 0, stream,
                       X, mask, Wb, Wp, bp, gE, bE, out);
}

// Round 7
// 251.781 us; speedup vs baseline: 4.4768x; 1.1186x over previous
//
#include <hip/hip_runtime.h>
#include <hip/hip_bf16.h>
#include <math.h>

// Outputs are FLOAT32. B=8, L=1024, K=30, F=128 -> flat offsets (f32 elements):
#define V_OFF    ((size_t)0)
#define E_OFF    ((size_t)1048576)
#define EIDX_OFF ((size_t)32505856)
#define BB_OFF   ((size_t)32751616)

#define K 30
#define NRBF 16
#define NGROUP 25
#define KPAD 416          // 13 * 32
#define AROW 424          // padded LDS row stride (bf16 elems) for bank spread
#define SSTR 132          // padded S stride (f32)

typedef __attribute__((ext_vector_type(8))) short bf16x8;
typedef __attribute__((ext_vector_type(4))) float f32x4;

// atom indices: N=0, Ca=1, C=2, CB=3, O=4
__device__ __constant__ int c_pairA[24] = {0,2,4,3,1,1,1,1,0,0,0,3,3,4,0,2,4,3,2,4,3,2,4,2};
__device__ __constant__ int c_pairB[24] = {0,2,4,3,0,2,4,3,2,4,3,2,4,2,1,1,1,1,0,0,0,3,3,4};

__device__ __forceinline__ unsigned short f2bu(float f) {   // RNE f32->bf16 bits (finite)
    unsigned x = __float_as_uint(f);
    return (unsigned short)((x + 0x7fffu + ((x >> 16) & 1u)) >> 16);
}

__device__ __forceinline__ void norm_to(const float v[3], float o[3]) {
    float n = sqrtf(v[0]*v[0] + v[1]*v[1] + v[2]*v[2]);
    n = fmaxf(n, 1e-12f);
    o[0] = v[0]/n; o[1] = v[1]/n; o[2] = v[2]/n;
}
__device__ __forceinline__ void unit_diff(const float a[3], const float b[3], float o[3]) {
    float v[3] = {a[0]-b[0], a[1]-b[1], a[2]-b[2]};
    norm_to(v, o);
}
__device__ __forceinline__ void cross_unit(const float a[3], const float b[3], float o[3]) {
    float c[3] = {a[1]*b[2]-a[2]*b[1], a[2]*b[0]-a[0]*b[2], a[0]*b[1]-a[1]*b[0]};
    norm_to(c, o);
}

// ---------------- kernel 0: We (400x128 f32) -> Wb fragment-major bf16 in ws ----------------
__global__ __launch_bounds__(128) void wb_prep_kernel(
    const float* __restrict__ We, unsigned short* __restrict__ Wb)
{
    const int s = blockIdx.x;          // 0..12
    const int j = threadIdx.x;         // 0..127
    unsigned* dst = (unsigned*)(Wb + ((size_t)(s*128 + j) << 5));
    #pragma unroll
    for (int m = 0; m < 16; ++m) {
        const int k0 = s*32 + 2*m;
        const unsigned lo = (k0   < 400) ? f2bu(We[(size_t)k0*128 + j])     : 0u;
        const unsigned hi = (k0+1 < 400) ? f2bu(We[(size_t)(k0+1)*128 + j]) : 0u;
        dst[m] = (hi << 16) | lo;
    }
}

// ---------------- kernel 1: node features (V) + bb + Ca float4 pack ----------------
__global__ __launch_bounds__(128) void node_bb_kernel(
    const float* __restrict__ X, const float* __restrict__ Wn,
    const float* __restrict__ gn, const float* __restrict__ bn,
    float* __restrict__ out, float4* __restrict__ ca4)
{
    const int blk = blockIdx.x;
    const int b = blk >> 10, i = blk & 1023;
    const int tid = threadIdx.x;
    __shared__ float ang[3];
    __shared__ float red[128];

    if (tid < 3) {
        const int m = 3*i + tid;
        float dang = 0.f;
        if (m >= 1 && m <= 3*1024 - 3) {
            const int t = m - 1;
            float P[4][3];
            #pragma unroll
            for (int q = 0; q < 4; ++q) {
                const int s = t + q;
                const int ri = s / 3, ai = s - 3*ri;
                const float* p = X + (((size_t)b * 1024 + ri) * 5 + ai) * 3;
                P[q][0] = p[0]; P[q][1] = p[1]; P[q][2] = p[2];
            }
            float u2v[3], u1v[3], u0v[3];
            unit_diff(P[1], P[0], u2v);
            unit_diff(P[2], P[1], u1v);
            unit_diff(P[3], P[2], u0v);
            float n2v[3], n1v[3];
            cross_unit(u2v, u1v, n2v);
            cross_unit(u1v, u0v, n1v);
            float cosD = n2v[0]*n1v[0] + n2v[1]*n1v[1] + n2v[2]*n1v[2];
            cosD = fminf(fmaxf(cosD, -1.f + 1e-7f), 1.f - 1e-7f);
            float sg = u2v[0]*n1v[0] + u2v[1]*n1v[1] + u2v[2]*n1v[2];
            float s = (sg > 0.f) ? 1.f : ((sg < 0.f) ? -1.f : 0.f);
            dang = s * acosf(cosD);
        }
        ang[tid] = dang;
    }
    if (tid == 3) {
        const float* p = X + (size_t)blk * 15;
        float Nx=p[0],  Ny=p[1],  Nz=p[2];
        float Cax=p[3], Cay=p[4], Caz=p[5];
        float Cx=p[6],  Cy=p[7],  Cz=p[8];
        ca4[blk] = make_float4(Cax, Cay, Caz, 0.f);
        float v1[3] = {Cx-Cax, Cy-Cay, Cz-Caz};
        float v2[3] = {Nx-Cax, Ny-Cay, Nz-Caz};
        float e1[3]; norm_to(v1, e1);
        float dd = e1[0]*v2[0] + e1[1]*v2[1] + e1[2]*v2[2];
        float u2[3] = {v2[0]-e1[0]*dd, v2[1]-e1[1]*dd, v2[2]-e1[2]*dd};
        float e2[3]; norm_to(u2, e2);
        float e3[3] = {e1[1]*e2[2]-e1[2]*e2[1], e1[2]*e2[0]-e1[0]*e2[2], e1[0]*e2[1]-e1[1]*e2[0]};
        float* bb = out + BB_OFF + (size_t)blk * 16;
        bb[0]=e1[0]; bb[1]=e1[1]; bb[2]=e1[2];  bb[3]=Cax;
        bb[4]=e2[0]; bb[5]=e2[1]; bb[6]=e2[2];  bb[7]=Cay;
        bb[8]=e3[0]; bb[9]=e3[1]; bb[10]=e3[2]; bb[11]=Caz;
        bb[12]=0.f; bb[13]=0.f; bb[14]=0.f; bb[15]=0.f;
    }
    __syncthreads();
    const float a0 = ang[0], a1 = ang[1], a2 = ang[2];
    float feat[6] = {cosf(a0), cosf(a1), cosf(a2), sinf(a0), sinf(a1), sinf(a2)};
    float x = 0.f;
    #pragma unroll
    for (int f = 0; f < 6; ++f) x += feat[f] * Wn[f*128 + tid];
    red[tid] = x; __syncthreads();
    for (int s = 64; s > 0; s >>= 1) { if (tid < s) red[tid] += red[tid+s]; __syncthreads(); }
    const float mean = red[0] * (1.f/128.f);
    __syncthreads();
    const float xm = x - mean;
    red[tid] = xm*xm; __syncthreads();
    for (int s = 64; s > 0; s >>= 1) { if (tid < s) red[tid] += red[tid+s]; __syncthreads(); }
    const float var = red[0] * (1.f/128.f);
    const float y = xm / __fsqrt_rn(var + 1e-5f) * gn[tid] + bn[tid];
    out[V_OFF + (size_t)blk * 128 + tid] = y;
}

// ---------------- kernel 2: fused top-k + edge features ----------------
__global__ __launch_bounds__(256) void topk_edge_kernel(
    const float* __restrict__ X, const float* __restrict__ mask,
    const unsigned short* __restrict__ Wb, const float* __restrict__ Wp,
    const float* __restrict__ bp, const float* __restrict__ ge,
    const float* __restrict__ be, const float4* __restrict__ ca4,
    float* __restrict__ out)
{
    const int blk = blockIdx.x;
    const int b = blk >> 10, i = blk & 1023;
    const int tid = threadIdx.x;
    const int w = tid >> 6, lane = tid & 63;

    __shared__ __align__(16) unsigned char smem_raw[32 * AROW * 2];  // 27136 B: A tile, later S
    __shared__ unsigned long long wl[4][K];     // per-wave local top-30 lists
    __shared__ float redf4[4];
    __shared__ float nbA[K][15];
    __shared__ int   nj[K];
    __shared__ float dnbv[K];
    unsigned short* A_lds = (unsigned short*)smem_raw;
    float* S = (float*)smem_raw;                 // union; guarded by barriers

    // ---- phase 1: masked distances (coalesced float4 Ca), keys in registers ----
    const float4 me = ca4[(b << 10) + i];
    const float mi  = mask[(b << 10) + i];

    float dv_r[4], m2_r[4];
    float lmax = -1.f;
    #pragma unroll
    for (int m = 0; m < 4; ++m) {
        const int j = tid + (m << 8);
        const float4 cj = ca4[(b << 10) + j];
        const float dx = __fsub_rn(me.x, cj.x);
        const float dy = __fsub_rn(me.y, cj.y);
        const float dz = __fsub_rn(me.z, cj.z);
        // numpy association order: ((dx^2+dy^2)+dz^2)+1e-6
        const float ss = __fadd_rn(__fadd_rn(__fmul_rn(dx,dx), __fmul_rn(dy,dy)), __fmul_rn(dz,dz));
        const float dist = __fsqrt_rn(__fadd_rn(ss, 1e-6f));
        const float m2 = __fmul_rn(mi, mask[(b << 10) + j]);
        const float Dv = __fmul_rn(m2, dist);
        dv_r[m] = Dv; m2_r[m] = m2;
        lmax = fmaxf(lmax, Dv);
    }
    #pragma unroll
    for (int s = 1; s < 64; s <<= 1) lmax = fmaxf(lmax, __shfl_xor(lmax, s));
    if (lane == 0) redf4[w] = lmax;
    __syncthreads();
    const float Dmax = fmaxf(fmaxf(redf4[0], redf4[1]), fmaxf(redf4[2], redf4[3]));

    float val[4];
    #pragma unroll
    for (int m = 0; m < 4; ++m)
        val[m] = __fadd_rn(dv_r[m], __fmul_rn(__fsub_rn(1.f, m2_r[m]), Dmax));

    // ---- per-wave local top-30: f32 value butterfly + ballot winner (exact) ----
    const float INF = __int_as_float(0x7f800000);
    for (int k = 0; k < K; ++k) {
        const float head = fminf(fminf(val[0], val[1]), fminf(val[2], val[3]));
        float v = head;
        #pragma unroll
        for (int s = 1; s < 64; s <<= 1) v = fminf(v, __shfl_xor(v, s));
        // local best slot (smallest m among slots == v)
        const int bm = (val[0] == v) ? 0 : (val[1] == v) ? 1 : (val[2] == v) ? 2 : 3;
        const int jc = (bm << 8) | tid;                 // global index j = 256m + tid
        const unsigned long long msk = __ballot(head == v);
        if (__popcll(msk) == 1) {
            const int winner = (int)(__ffsll((long long)msk) - 1);
            const int jw = __shfl(jc, winner);
            if (lane == winner) val[bm] = INF;
            if (lane == 0) wl[w][k] = ((unsigned long long)__float_as_uint(v) << 32) | (unsigned)jw;
        } else {
            // rare: bit-equal distances in multiple lanes -> exact index tie-break
            int jt = (head == v) ? jc : 0x7fffffff;
            #pragma unroll
            for (int s = 1; s < 64; s <<= 1) jt = min(jt, __shfl_xor(jt, s));
            if (head == v && jc == jt) val[bm] = INF;
            if (lane == 0) wl[w][k] = ((unsigned long long)__float_as_uint(v) << 32) | (unsigned)jt;
        }
    }
    __syncthreads();

    // ---- 4-way merge of sorted lists (wave 0; lanes redundant, lane 0 writes) ----
    if (w == 0) {
        int h0 = 0, h1 = 0, h2 = 0, h3 = 0;
        for (int k = 0; k < K; ++k) {
            const unsigned long long c0 = wl[0][h0], c1 = wl[1][h1];
            const unsigned long long c2 = wl[2][h2], c3 = wl[3][h3];
            unsigned long long mb = c0 < c1 ? c0 : c1;
            const unsigned long long m23 = c2 < c3 ? c2 : c3;
            mb = mb < m23 ? mb : m23;
            if (lane == 0) {
                const int j = (int)(mb & 0xffffffffu);
                nj[k] = j;
                dnbv[k] = __uint_as_float((unsigned)(mb >> 32));
                out[EIDX_OFF + (size_t)blk * K + k] = (float)j;
            }
            if (mb == c0) ++h0; else if (mb == c1) ++h1; else if (mb == c2) ++h2; else ++h3;
        }
    }
    __syncthreads();

    // ---- phase 2a: zero A pad region + fetch neighbor atoms ----
    {
        unsigned* az = (unsigned*)A_lds;
        for (int t = tid; t < 32*8; t += 256) { const int r = t >> 3, c = t & 7; az[r*212 + 200 + c] = 0u; }
        for (int t = tid; t < 400; t += 256) { const int r = 30 + (t >= 200), c = t % 200; az[r*212 + c] = 0u; }
    }
    for (int t = tid; t < K*15; t += 256) {
        const int e = t / 15, r = t - e*15;
        nbA[e][r] = X[((size_t)(b << 10) + nj[e])*15 + r];
    }
    __syncthreads();

    // ---- phase 2b: rbf -> bf16 A tile ----
    const float* sa = X + (size_t)blk * 15;
    for (int t = tid; t < K*NGROUP; t += 256) {
        const int e = t / NGROUP, g = t - e*NGROUP;
        float d;
        if (g == 0) d = dnbv[e];
        else {
            const int p = g - 1;
            const int aA = c_pairA[p], aB = c_pairB[p];
            const float dx = sa[aA*3+0] - nbA[e][aB*3+0];
            const float dy = sa[aA*3+1] - nbA[e][aB*3+1];
            const float dz = sa[aA*3+2] - nbA[e][aB*3+2];
            d = sqrtf(dx*dx + dy*dy + dz*dz + 1e-6f);
        }
        unsigned* dst = (unsigned*)A_lds + (e*AROW + g*NRBF)/2;
        #pragma unroll
        for (int m = 0; m < 8; ++m) {
            const float mu0 = 2.f + (2*m)   * (4.f/3.f);
            const float mu1 = 2.f + (2*m+1) * (4.f/3.f);
            const float z0 = (d - mu0) * 0.8f;
            const float z1 = (d - mu1) * 0.8f;
            const unsigned lo = f2bu(__expf(-z0*z0));
            const unsigned hi = f2bu(__expf(-z1*z1));
            dst[m] = (hi << 16) | lo;
        }
    }
    __syncthreads();

    // ---- phase 2c: MFMA (32x416) @ (416x128); wave w owns N columns [32w, 32w+32) ----
    f32x4 acc00 = {0,0,0,0}, acc01 = {0,0,0,0}, acc10 = {0,0,0,0}, acc11 = {0,0,0,0};
    {
        const int ar = lane & 15;          // A row within tile / B col within tile
        const int kg = (lane >> 4) * 8;    // k-offset group
        const unsigned short* a_base = A_lds + ar*AROW + kg;
        const unsigned short* b_base = Wb + ((size_t)(w*32 + ar) << 5) + kg;
        for (int s = 0; s < 13; ++s) {
            const bf16x8 a0 = *reinterpret_cast<const bf16x8*>(a_base + s*32);
            const bf16x8 a1 = *reinterpret_cast<const bf16x8*>(a_base + 16*AROW + s*32);
            const bf16x8 b0 = *reinterpret_cast<const bf16x8*>(b_base + (size_t)s*4096);
            const bf16x8 b1 = *reinterpret_cast<const bf16x8*>(b_base + (size_t)s*4096 + 512);
            acc00 = __builtin_amdgcn_mfma_f32_16x16x32_bf16(a0, b0, acc00, 0, 0, 0);
            acc01 = __builtin_amdgcn_mfma_f32_16x16x32_bf16(a0, b1, acc01, 0, 0, 0);
            acc10 = __builtin_amdgcn_mfma_f32_16x16x32_bf16(a1, b0, acc10, 0, 0, 0);
            acc11 = __builtin_amdgcn_mfma_f32_16x16x32_bf16(a1, b1, acc11, 0, 0, 0);
        }
    }
    __syncthreads();                       // all A reads complete; smem becomes S
    {
        // C layout (m89): col = lane&15, row = (lane>>4)*4 + reg
        const int crow = (lane >> 4) * 4;
        const int ccol = w*32 + (lane & 15);
        #pragma unroll
        for (int r = 0; r < 4; ++r) {
            const int r0 = crow + r;
            if (r0 < K) { S[r0*SSTR + ccol] = acc00[r]; S[r0*SSTR + ccol + 16] = acc01[r]; }
            const int r1 = 16 + crow + r;
            if (r1 < K) { S[r1*SSTR + ccol] = acc10[r]; S[r1*SSTR + ccol + 16] = acc11[r]; }
        }
    }
    __syncthreads();

    // ---- phase 2d: + positional embedding + bias ----
    for (int t = tid; t < K*128; t += 256) {
        const int e = t >> 7, j = t & 127;
        int off = i - nj[e] + 32;
        off = off < 0 ? 0 : (off > 64 ? 64 : off);
        S[e*SSTR + j] += Wp[off*128 + j] + bp[j];
    }
    __syncthreads();

    // ---- phase 2e: per-edge LayerNorm ----
    const float inv128 = 1.f/128.f;
    for (int e = w; e < K; e += 4) {
        const float x0 = S[e*SSTR + lane], x1 = S[e*SSTR + lane + 64];
        float sum = x0 + x1;
        #pragma unroll
        for (int s = 32; s > 0; s >>= 1) sum += __shfl_xor(sum, s);
        const float mean = sum * inv128;
        const float d0 = x0 - mean, d1 = x1 - mean;
        float vs = d0*d0 + d1*d1;
        #pragma unroll
        for (int s = 32; s > 0; s >>= 1) vs += __shfl_xor(vs, s);
        const float inv = 1.f / __fsqrt_rn(vs * inv128 + 1e-5f);
        const size_t base = E_OFF + ((size_t)blk * K + e) * 128;
        out[base + lane]      = d0 * inv * ge[lane]      + be[lane];
        out[base + lane + 64] = d1 * inv * ge[lane + 64] + be[lane + 64];
    }
}

extern "C" void kernel_launch(void* const* d_in, const int* in_sizes, int n_in,
                              void* d_out, int out_size, void* d_ws, size_t ws_size,
                              hipStream_t stream) {
    const float* X    = (const float*)d_in[0];
    const float* mask = (const float*)d_in[1];
    // d_in[2] = Lvec (int32), unused
    const float* We   = (const float*)d_in[3];
    const float* Wn   = (const float*)d_in[4];
    const float* Wp   = (const float*)d_in[5];
    const float* bp   = (const float*)d_in[6];
    const float* gE   = (const float*)d_in[7];
    const float* bE   = (const float*)d_in[8];
    const float* gN   = (const float*)d_in[9];
    const float* bN   = (const float*)d_in[10];
    float* out = (float*)d_out;
    unsigned short* Wb = (unsigned short*)d_ws;                    // 106,496 B
    float4* ca4 = (float4*)((char*)d_ws + 106496);                 // 8192 * 16 B

    hipLaunchKernelGGL(wb_prep_kernel,   dim3(13),   dim3(128), 0, stream, We, Wb);
    hipLaunchKernelGGL(node_bb_kernel,   dim3(8192), dim3(128), 0, stream, X, Wn, gN, bN, out, ca4);
    hipLaunchKernelGGL(topk_edge_kernel, dim3(8192), dim3(256), 0, stream,
                       X, mask, Wb, Wp, bp, gE, bE, ca4, out);
}

// Round 8
// 176.120 us; speedup vs baseline: 6.4000x; 1.4296x over previous
//
#include <hip/hip_runtime.h>
#include <hip/hip_bf16.h>
#include <math.h>

// Outputs are FLOAT32. B=8, L=1024, K=30, F=128 -> flat offsets (f32 elements):
#define V_OFF    ((size_t)0)
#define E_OFF    ((size_t)1048576)
#define EIDX_OFF ((size_t)32505856)
#define BB_OFF   ((size_t)32751616)

#define K 30
#define NRBF 16
#define AH   232          // A-half LDS row stride in bf16 (464 B -> 20-bank rotation, 2-way max)
#define SSTR 132          // padded S stride (f32)

typedef __attribute__((ext_vector_type(8))) short bf16x8;
typedef __attribute__((ext_vector_type(4))) float f32x4;

// atom indices: N=0, Ca=1, C=2, CB=3, O=4
__device__ __constant__ int c_pairA[24] = {0,2,4,3,1,1,1,1,0,0,0,3,3,4,0,2,4,3,2,4,3,2,4,2};
__device__ __constant__ int c_pairB[24] = {0,2,4,3,0,2,4,3,2,4,3,2,4,2,1,1,1,1,0,0,0,3,3,4};

// mu_k * 0.8 * sqrt(log2(e)) for exp2-folded RBF
__device__ __constant__ float c_muS[16] = {
    1.92179871f, 3.20299785f, 4.48419699f, 5.76539613f, 7.04659527f, 8.32779441f,
    9.60899355f, 10.89019269f, 12.17139183f, 13.45259097f, 14.73379011f, 16.01498925f,
    17.29618839f, 18.57738753f, 19.85858667f, 21.13978581f};

__device__ __forceinline__ unsigned short f2bu(float f) {   // RNE f32->bf16 bits (finite)
    unsigned x = __float_as_uint(f);
    return (unsigned short)((x + 0x7fffu + ((x >> 16) & 1u)) >> 16);
}

// ---- DPP wave-64 reductions (result broadcast via lane 63 readlane) ----
__device__ __forceinline__ unsigned wave_umin64(unsigned x) {
    unsigned t;
    t = __builtin_amdgcn_update_dpp(x, x, 0x111, 0xf, 0xf, false); x = min(x, t);
    t = __builtin_amdgcn_update_dpp(x, x, 0x112, 0xf, 0xf, false); x = min(x, t);
    t = __builtin_amdgcn_update_dpp(x, x, 0x114, 0xf, 0xf, false); x = min(x, t);
    t = __builtin_amdgcn_update_dpp(x, x, 0x118, 0xf, 0xf, false); x = min(x, t);
    t = __builtin_amdgcn_update_dpp(x, x, 0x142, 0xf, 0xf, false); x = min(x, t);
    t = __builtin_amdgcn_update_dpp(x, x, 0x143, 0xf, 0xf, false); x = min(x, t);
    return (unsigned)__builtin_amdgcn_readlane((int)x, 63);
}
__device__ __forceinline__ unsigned wave_umax64(unsigned x) {
    unsigned t;
    t = __builtin_amdgcn_update_dpp(x, x, 0x111, 0xf, 0xf, false); x = max(x, t);
    t = __builtin_amdgcn_update_dpp(x, x, 0x112, 0xf, 0xf, false); x = max(x, t);
    t = __builtin_amdgcn_update_dpp(x, x, 0x114, 0xf, 0xf, false); x = max(x, t);
    t = __builtin_amdgcn_update_dpp(x, x, 0x118, 0xf, 0xf, false); x = max(x, t);
    t = __builtin_amdgcn_update_dpp(x, x, 0x142, 0xf, 0xf, false); x = max(x, t);
    t = __builtin_amdgcn_update_dpp(x, x, 0x143, 0xf, 0xf, false); x = max(x, t);
    return (unsigned)__builtin_amdgcn_readlane((int)x, 63);
}
__device__ __forceinline__ float wave_fadd64(float x) {
    float t;
    t = __int_as_float(__builtin_amdgcn_update_dpp(0, __float_as_int(x), 0x111, 0xf, 0xf, true)); x += t;
    t = __int_as_float(__builtin_amdgcn_update_dpp(0, __float_as_int(x), 0x112, 0xf, 0xf, true)); x += t;
    t = __int_as_float(__builtin_amdgcn_update_dpp(0, __float_as_int(x), 0x114, 0xf, 0xf, true)); x += t;
    t = __int_as_float(__builtin_amdgcn_update_dpp(0, __float_as_int(x), 0x118, 0xf, 0xf, true)); x += t;
    t = __int_as_float(__builtin_amdgcn_update_dpp(0, __float_as_int(x), 0x142, 0xf, 0xf, true)); x += t;
    t = __int_as_float(__builtin_amdgcn_update_dpp(0, __float_as_int(x), 0x143, 0xf, 0xf, true)); x += t;
    return __int_as_float(__builtin_amdgcn_readlane(__float_as_int(x), 63));
}

__device__ __forceinline__ void norm_to(const float v[3], float o[3]) {
    float n = sqrtf(v[0]*v[0] + v[1]*v[1] + v[2]*v[2]);
    n = fmaxf(n, 1e-12f);
    o[0] = v[0]/n; o[1] = v[1]/n; o[2] = v[2]/n;
}
__device__ __forceinline__ void unit_diff(const float a[3], const float b[3], float o[3]) {
    float v[3] = {a[0]-b[0], a[1]-b[1], a[2]-b[2]};
    norm_to(v, o);
}
__device__ __forceinline__ void cross_unit(const float a[3], const float b[3], float o[3]) {
    float c[3] = {a[1]*b[2]-a[2]*b[1], a[2]*b[0]-a[0]*b[2], a[0]*b[1]-a[1]*b[0]};
    norm_to(c, o);
}

// ---------------- kernel 0: We (400x128 f32) -> Wb fragment-major bf16 in ws ----------------
__global__ __launch_bounds__(128) void wb_prep_kernel(
    const float* __restrict__ We, unsigned short* __restrict__ Wb)
{
    const int s = blockIdx.x;          // 0..12
    const int j = threadIdx.x;         // 0..127
    unsigned* dst = (unsigned*)(Wb + ((size_t)(s*128 + j) << 5));
    #pragma unroll
    for (int m = 0; m < 16; ++m) {
        const int k0 = s*32 + 2*m;
        const unsigned lo = (k0   < 400) ? f2bu(We[(size_t)k0*128 + j])     : 0u;
        const unsigned hi = (k0+1 < 400) ? f2bu(We[(size_t)(k0+1)*128 + j]) : 0u;
        dst[m] = (hi << 16) | lo;
    }
}

// ---------------- kernel 1: node features (V) + bb + Ca float4 pack ----------------
__global__ __launch_bounds__(128) void node_bb_kernel(
    const float* __restrict__ X, const float* __restrict__ Wn,
    const float* __restrict__ gn, const float* __restrict__ bn,
    float* __restrict__ out, float4* __restrict__ ca4)
{
    const int blk = blockIdx.x;
    const int b = blk >> 10, i = blk & 1023;
    const int tid = threadIdx.x;
    __shared__ float ang[3];
    __shared__ float red[128];

    if (tid < 3) {
        const int m = 3*i + tid;
        float dang = 0.f;
        if (m >= 1 && m <= 3*1024 - 3) {
            const int t = m - 1;
            float P[4][3];
            #pragma unroll
            for (int q = 0; q < 4; ++q) {
                const int s = t + q;
                const int ri = s / 3, ai = s - 3*ri;
                const float* p = X + (((size_t)b * 1024 + ri) * 5 + ai) * 3;
                P[q][0] = p[0]; P[q][1] = p[1]; P[q][2] = p[2];
            }
            float u2v[3], u1v[3], u0v[3];
            unit_diff(P[1], P[0], u2v);
            unit_diff(P[2], P[1], u1v);
            unit_diff(P[3], P[2], u0v);
            float n2v[3], n1v[3];
            cross_unit(u2v, u1v, n2v);
            cross_unit(u1v, u0v, n1v);
            float cosD = n2v[0]*n1v[0] + n2v[1]*n1v[1] + n2v[2]*n1v[2];
            cosD = fminf(fmaxf(cosD, -1.f + 1e-7f), 1.f - 1e-7f);
            float sg = u2v[0]*n1v[0] + u2v[1]*n1v[1] + u2v[2]*n1v[2];
            float s = (sg > 0.f) ? 1.f : ((sg < 0.f) ? -1.f : 0.f);
            dang = s * acosf(cosD);
        }
        ang[tid] = dang;
    }
    if (tid == 3) {
        const float* p = X + (size_t)blk * 15;
        float Nx=p[0],  Ny=p[1],  Nz=p[2];
        float Cax=p[3], Cay=p[4], Caz=p[5];
        float Cx=p[6],  Cy=p[7],  Cz=p[8];
        ca4[blk] = make_float4(Cax, Cay, Caz, 0.f);
        float v1[3] = {Cx-Cax, Cy-Cay, Cz-Caz};
        float v2[3] = {Nx-Cax, Ny-Cay, Nz-Caz};
        float e1[3]; norm_to(v1, e1);
        float dd = e1[0]*v2[0] + e1[1]*v2[1] + e1[2]*v2[2];
        float u2[3] = {v2[0]-e1[0]*dd, v2[1]-e1[1]*dd, v2[2]-e1[2]*dd};
        float e2[3]; norm_to(u2, e2);
        float e3[3] = {e1[1]*e2[2]-e1[2]*e2[1], e1[2]*e2[0]-e1[0]*e2[2], e1[0]*e2[1]-e1[1]*e2[0]};
        float* bb = out + BB_OFF + (size_t)blk * 16;
        bb[0]=e1[0]; bb[1]=e1[1]; bb[2]=e1[2];  bb[3]=Cax;
        bb[4]=e2[0]; bb[5]=e2[1]; bb[6]=e2[2];  bb[7]=Cay;
        bb[8]=e3[0]; bb[9]=e3[1]; bb[10]=e3[2]; bb[11]=Caz;
        bb[12]=0.f; bb[13]=0.f; bb[14]=0.f; bb[15]=0.f;
    }
    __syncthreads();
    const float a0 = ang[0], a1 = ang[1], a2 = ang[2];
    float feat[6] = {cosf(a0), cosf(a1), cosf(a2), sinf(a0), sinf(a1), sinf(a2)};
    float x = 0.f;
    #pragma unroll
    for (int f = 0; f < 6; ++f) x += feat[f] * Wn[f*128 + tid];
    red[tid] = x; __syncthreads();
    for (int s = 64; s > 0; s >>= 1) { if (tid < s) red[tid] += red[tid+s]; __syncthreads(); }
    const float mean = red[0] * (1.f/128.f);
    __syncthreads();
    const float xm = x - mean;
    red[tid] = xm*xm; __syncthreads();
    for (int s = 64; s > 0; s >>= 1) { if (tid < s) red[tid] += red[tid+s]; __syncthreads(); }
    const float var = red[0] * (1.f/128.f);
    const float y = xm / __fsqrt_rn(var + 1e-5f) * gn[tid] + bn[tid];
    out[V_OFF + (size_t)blk * 128 + tid] = y;
}

// ---------------- kernel 2: fused top-k + edge features ----------------
__global__ __launch_bounds__(256, 8) void topk_edge_kernel(
    const float* __restrict__ X, const float* __restrict__ mask,
    const unsigned short* __restrict__ Wb, const float* __restrict__ Wp,
    const float* __restrict__ bp, const float* __restrict__ ge,
    const float* __restrict__ be, const float4* __restrict__ ca4,
    float* __restrict__ out)
{
    const int blk = blockIdx.x;
    const int b = blk >> 10, i = blk & 1023;
    const int tid = threadIdx.x;
    const int w = tid >> 6, lane = tid & 63;

    __shared__ __align__(16) unsigned char uni_raw[K * SSTR * 4];  // 15840 B: A-half (14848) / S union
    __shared__ unsigned long long wl[4][K];
    __shared__ float redf4[4];
    __shared__ float nbA[K][15];
    __shared__ int   nj[K];
    __shared__ float dnbv[K];
    unsigned short* A_lds = (unsigned short*)uni_raw;
    float* S = (float*)uni_raw;

    // ---- phase 1: masked distances (coalesced float4 Ca) ----
    const float4 me = ca4[(b << 10) + i];
    const float mi  = mask[(b << 10) + i];

    float dv_r[4], m2_r[4];
    float lmax = -1.f;
    #pragma unroll
    for (int m = 0; m < 4; ++m) {
        const int j = tid + (m << 8);
        const float4 cj = ca4[(b << 10) + j];
        const float dx = __fsub_rn(me.x, cj.x);
        const float dy = __fsub_rn(me.y, cj.y);
        const float dz = __fsub_rn(me.z, cj.z);
        // numpy association order: ((dx^2+dy^2)+dz^2)+1e-6
        const float ss = __fadd_rn(__fadd_rn(__fmul_rn(dx,dx), __fmul_rn(dy,dy)), __fmul_rn(dz,dz));
        const float dist = __fsqrt_rn(__fadd_rn(ss, 1e-6f));
        const float m2 = __fmul_rn(mi, mask[(b << 10) + j]);
        const float Dv = __fmul_rn(m2, dist);
        dv_r[m] = Dv; m2_r[m] = m2;
        lmax = fmaxf(lmax, Dv);
    }
    // Dv >= 0 -> u32 order == float order
    const float wmax = __uint_as_float(wave_umax64(__float_as_uint(lmax)));
    if (lane == 0) redf4[w] = wmax;
    __syncthreads();
    const float Dmax = fmaxf(fmaxf(redf4[0], redf4[1]), fmaxf(redf4[2], redf4[3]));

    unsigned va[4];
    #pragma unroll
    for (int m = 0; m < 4; ++m)
        va[m] = __float_as_uint(__fadd_rn(dv_r[m], __fmul_rn(__fsub_rn(1.f, m2_r[m]), Dmax)));

    // ---- per-wave local top-30: DPP u32-min butterfly + ballot winner (exact) ----
    for (int k = 0; k < K; ++k) {
        const unsigned head = min(min(va[0], va[1]), min(va[2], va[3]));
        const unsigned v = wave_umin64(head);
        const int bm = (va[0] == v) ? 0 : (va[1] == v) ? 1 : (va[2] == v) ? 2 : 3;
        const unsigned jc = ((unsigned)bm << 8) | (unsigned)tid;   // global candidate index
        const unsigned long long msk = __ballot(head == v);
        unsigned jw;
        if (__popcll(msk) == 1) {
            const int winner = (int)(__ffsll((long long)msk) - 1);
            jw = (unsigned)__builtin_amdgcn_readlane((int)jc, winner);
            if (lane == winner) {
                va[0] = (bm == 0) ? 0xffffffffu : va[0];
                va[1] = (bm == 1) ? 0xffffffffu : va[1];
                va[2] = (bm == 2) ? 0xffffffffu : va[2];
                va[3] = (bm == 3) ? 0xffffffffu : va[3];
            }
        } else {
            // rare: bit-equal values in multiple lanes -> exact smallest-index tie-break
            jw = wave_umin64((head == v) ? jc : 0xffffffffu);
            if (head == v && jc == jw) {
                va[0] = (bm == 0) ? 0xffffffffu : va[0];
                va[1] = (bm == 1) ? 0xffffffffu : va[1];
                va[2] = (bm == 2) ? 0xffffffffu : va[2];
                va[3] = (bm == 3) ? 0xffffffffu : va[3];
            }
        }
        if (lane == 0) wl[w][k] = ((unsigned long long)v << 32) | jw;
    }
    __syncthreads();

    // ---- 4-way merge of sorted lists (wave 0; lanes redundant, lane 0 writes) ----
    if (w == 0) {
        int h0 = 0, h1 = 0, h2 = 0, h3 = 0;
        for (int k = 0; k < K; ++k) {
            const unsigned long long c0 = wl[0][h0], c1 = wl[1][h1];
            const unsigned long long c2 = wl[2][h2], c3 = wl[3][h3];
            unsigned long long mb = c0 < c1 ? c0 : c1;
            const unsigned long long m23 = c2 < c3 ? c2 : c3;
            mb = mb < m23 ? mb : m23;
            if (lane == 0) {
                const int j = (int)(mb & 0xffffffffu);
                nj[k] = j;
                dnbv[k] = __uint_as_float((unsigned)(mb >> 32));
                out[EIDX_OFF + (size_t)blk * K + k] = (float)j;
            }
            if (mb == c0) ++h0; else if (mb == c1) ++h1; else if (mb == c2) ++h2; else ++h3;
        }
    }
    __syncthreads();

    // ---- fetch neighbor atoms ----
    for (int t = tid; t < K*15; t += 256) {
        const int e = t / 15, r = t - e*15;
        nbA[e][r] = X[((size_t)(b << 10) + nj[e])*15 + r];
    }
    __syncthreads();

    const float* sa = X + (size_t)blk * 15;
    f32x4 acc00 = {0,0,0,0}, acc01 = {0,0,0,0}, acc10 = {0,0,0,0}, acc11 = {0,0,0,0};
    const int ar = lane & 15;
    const int kg = (lane >> 4) * 8;
    const unsigned short* a_base = A_lds + ar*AH + kg;
    const unsigned short* a_base1 = a_base + 16*AH;
    const unsigned short* b_base = Wb + ((size_t)(w*32 + ar) << 5) + kg;

    // ================= PASS 1: g in [0,12), k-global [0,192) =================
    for (int t = tid; t < K*12; t += 256) {
        const int e = t / 12, g = t - e*12;
        float d;
        if (g == 0) d = dnbv[e];
        else {
            const int p = g - 1;
            const int aA = c_pairA[p], aB = c_pairB[p];
            const float dx = sa[aA*3+0] - nbA[e][aB*3+0];
            const float dy = sa[aA*3+1] - nbA[e][aB*3+1];
            const float dz = sa[aA*3+2] - nbA[e][aB*3+2];
            d = sqrtf(dx*dx + dy*dy + dz*dz + 1e-6f);
        }
        const float t1 = d * 0.96089935f;
        unsigned* dst = (unsigned*)(A_lds + e*AH + g*NRBF);
        #pragma unroll
        for (int m = 0; m < 8; ++m) {
            const float z0 = t1 - c_muS[2*m];
            const float z1 = t1 - c_muS[2*m+1];
            const float v0 = exp2f(-z0*z0);
            const float v1 = exp2f(-z1*z1);
            unsigned pk;
            asm("v_cvt_pk_bf16_f32 %0, %1, %2" : "=v"(pk) : "v"(v0), "v"(v1));
            dst[m] = pk;
        }
    }
    __syncthreads();
    #pragma unroll
    for (int s = 0; s < 6; ++s) {
        const bf16x8 a0 = *reinterpret_cast<const bf16x8*>(a_base + s*32);
        const bf16x8 a1 = *reinterpret_cast<const bf16x8*>(a_base1 + s*32);
        const bf16x8 b0 = *reinterpret_cast<const bf16x8*>(b_base + (size_t)s*4096);
        const bf16x8 b1 = *reinterpret_cast<const bf16x8*>(b_base + (size_t)s*4096 + 512);
        acc00 = __builtin_amdgcn_mfma_f32_16x16x32_bf16(a0, b0, acc00, 0, 0, 0);
        acc01 = __builtin_amdgcn_mfma_f32_16x16x32_bf16(a0, b1, acc01, 0, 0, 0);
        acc10 = __builtin_amdgcn_mfma_f32_16x16x32_bf16(a1, b0, acc10, 0, 0, 0);
        acc11 = __builtin_amdgcn_mfma_f32_16x16x32_bf16(a1, b1, acc11, 0, 0, 0);
    }
    __syncthreads();   // pass-1 A reads complete

    // ================= PASS 2: g in [12,25), k-global [192,400)+pad =================
    for (int t = tid; t < K*13; t += 256) {
        const int e = t / 13, gg = t - e*13;
        const int p = 11 + gg;                 // pair index g-1, g = 12+gg
        const int aA = c_pairA[p], aB = c_pairB[p];
        const float dx = sa[aA*3+0] - nbA[e][aB*3+0];
        const float dy = sa[aA*3+1] - nbA[e][aB*3+1];
        const float dz = sa[aA*3+2] - nbA[e][aB*3+2];
        const float d = sqrtf(dx*dx + dy*dy + dz*dz + 1e-6f);
        const float t1 = d * 0.96089935f;
        unsigned* dst = (unsigned*)(A_lds + e*AH + gg*NRBF);
        #pragma unroll
        for (int m = 0; m < 8; ++m) {
            const float z0 = t1 - c_muS[2*m];
            const float z1 = t1 - c_muS[2*m+1];
            const float v0 = exp2f(-z0*z0);
            const float v1 = exp2f(-z1*z1);
            unsigned pk;
            asm("v_cvt_pk_bf16_f32 %0, %1, %2" : "=v"(pk) : "v"(v0), "v"(v1));
            dst[m] = pk;
        }
    }
    // zero k-local pad [208,224) for data rows 0..29 (rows 30/31 feed discarded C rows)
    for (int t = tid; t < K*8; t += 256) {
        const int e = t >> 3, c = t & 7;
        ((unsigned*)(A_lds + e*AH + 208))[c] = 0u;
    }
    __syncthreads();
    #pragma unroll
    for (int s = 0; s < 7; ++s) {
        const bf16x8 a0 = *reinterpret_cast<const bf16x8*>(a_base + s*32);
        const bf16x8 a1 = *reinterpret_cast<const bf16x8*>(a_base1 + s*32);
        const bf16x8 b0 = *reinterpret_cast<const bf16x8*>(b_base + (size_t)(6+s)*4096);
        const bf16x8 b1 = *reinterpret_cast<const bf16x8*>(b_base + (size_t)(6+s)*4096 + 512);
        acc00 = __builtin_amdgcn_mfma_f32_16x16x32_bf16(a0, b0, acc00, 0, 0, 0);
        acc01 = __builtin_amdgcn_mfma_f32_16x16x32_bf16(a0, b1, acc01, 0, 0, 0);
        acc10 = __builtin_amdgcn_mfma_f32_16x16x32_bf16(a1, b0, acc10, 0, 0, 0);
        acc11 = __builtin_amdgcn_mfma_f32_16x16x32_bf16(a1, b1, acc11, 0, 0, 0);
    }
    __syncthreads();   // pass-2 A reads complete; union region becomes S

    {
        // C layout (m89): col = lane&15, row = (lane>>4)*4 + reg
        const int crow = (lane >> 4) * 4;
        const int ccol = w*32 + (lane & 15);
        #pragma unroll
        for (int r = 0; r < 4; ++r) {
            const int r0 = crow + r;
            if (r0 < K) { S[r0*SSTR + ccol] = acc00[r]; S[r0*SSTR + ccol + 16] = acc01[r]; }
            const int r1 = 16 + crow + r;
            if (r1 < K) { S[r1*SSTR + ccol] = acc10[r]; S[r1*SSTR + ccol + 16] = acc11[r]; }
        }
    }
    __syncthreads();

    // ---- positional embedding + bias ----
    {
        const int j = tid & 127;
        const float bpj = bp[j];
        #pragma unroll
        for (int n = 0; n < 15; ++n) {
            const int e = (tid >> 7) + 2*n;
            int off = i - nj[e] + 32;
            off = off < 0 ? 0 : (off > 64 ? 64 : off);
            S[e*SSTR + j] += Wp[off*128 + j] + bpj;
        }
    }
    __syncthreads();

    // ---- per-edge LayerNorm (DPP reductions) ----
    const float inv128 = 1.f/128.f;
    const float g0 = ge[lane], g1 = ge[lane + 64];
    const float b0 = be[lane], b1 = be[lane + 64];
    for (int e = w; e < K; e += 4) {
        const float x0 = S[e*SSTR + lane], x1 = S[e*SSTR + lane + 64];
        const float mean = wave_fadd64(x0 + x1) * inv128;
        const float d0 = x0 - mean, d1 = x1 - mean;
        const float vs = wave_fadd64(d0*d0 + d1*d1);
        const float inv = 1.f / __fsqrt_rn(vs * inv128 + 1e-5f);
        const size_t base = E_OFF + ((size_t)blk * K + e) * 128;
        out[base + lane]      = d0 * inv * g0 + b0;
        out[base + lane + 64] = d1 * inv * g1 + b1;
    }
}

extern "C" void kernel_launch(void* const* d_in, const int* in_sizes, int n_in,
                              void* d_out, int out_size, void* d_ws, size_t ws_size,
                              hipStream_t stream) {
    const float* X    = (const float*)d_in[0];
    const float* mask = (const float*)d_in[1];
    // d_in[2] = Lvec (int32), unused
    const float* We   = (const float*)d_in[3];
    const float* Wn   = (const float*)d_in[4];
    const float* Wp   = (const float*)d_in[5];
    const float* bp   = (const float*)d_in[6];
    const float* gE   = (const float*)d_in[7];
    const float* bE   = (const float*)d_in[8];
    const float* gN   = (const float*)d_in[9];
    const float* bN   = (const float*)d_in[10];
    float* out = (float*)d_out;
    unsigned short* Wb = (unsigned short*)d_ws;                    // 106,496 B
    float4* ca4 = (float4*)((char*)d_ws + 106496);                 // 8192 * 16 B

    hipLaunchKernelGGL(wb_prep_kernel,   dim3(13),   dim3(128), 0, stream, We, Wb);
    hipLaunchKernelGGL(node_bb_kernel,   dim3(8192), dim3(128), 0, stream, X, Wn, gN, bN, out, ca4);
    hipLaunchKernelGGL(topk_edge_kernel, dim3(8192), dim3(256), 0, stream,
                       X, mask, Wb, Wp, bp, gE, bE, ca4, out);
}

// Round 9
// 165.743 us; speedup vs baseline: 6.8007x; 1.0626x over previous
//
#include <hip/hip_runtime.h>
#include <hip/hip_bf16.h>
#include <math.h>

// Outputs are FLOAT32. B=8, L=1024, K=30, F=128 -> flat offsets (f32 elements):
#define V_OFF    ((size_t)0)
#define E_OFF    ((size_t)1048576)
#define EIDX_OFF ((size_t)32505856)
#define BB_OFF   ((size_t)32751616)

#define K 30
#define NRBF 16
#define AH   232          // A-half LDS row stride in bf16
#define SSTR 132          // padded S stride (f32)

typedef __attribute__((ext_vector_type(8))) short bf16x8;
typedef __attribute__((ext_vector_type(4))) float f32x4;

// atom indices: N=0, Ca=1, C=2, CB=3, O=4
__device__ __constant__ int c_pairA[24] = {0,2,4,3,1,1,1,1,0,0,0,3,3,4,0,2,4,3,2,4,3,2,4,2};
__device__ __constant__ int c_pairB[24] = {0,2,4,3,0,2,4,3,2,4,3,2,4,2,1,1,1,1,0,0,0,3,3,4};

// mu_k * 0.8 * sqrt(log2(e)) for exp2-folded RBF
__device__ __constant__ float c_muS[16] = {
    1.92179871f, 3.20299785f, 4.48419699f, 5.76539613f, 7.04659527f, 8.32779441f,
    9.60899355f, 10.89019269f, 12.17139183f, 13.45259097f, 14.73379011f, 16.01498925f,
    17.29618839f, 18.57738753f, 19.85858667f, 21.13978581f};

__device__ __forceinline__ unsigned short f2bu(float f) {   // RNE f32->bf16 bits (finite)
    unsigned x = __float_as_uint(f);
    return (unsigned short)((x + 0x7fffu + ((x >> 16) & 1u)) >> 16);
}

// ---- DPP wave-64 reductions ----
__device__ __forceinline__ unsigned wave_umin64(unsigned x) {
    unsigned t;
    t = __builtin_amdgcn_update_dpp(x, x, 0x111, 0xf, 0xf, false); x = min(x, t);
    t = __builtin_amdgcn_update_dpp(x, x, 0x112, 0xf, 0xf, false); x = min(x, t);
    t = __builtin_amdgcn_update_dpp(x, x, 0x114, 0xf, 0xf, false); x = min(x, t);
    t = __builtin_amdgcn_update_dpp(x, x, 0x118, 0xf, 0xf, false); x = min(x, t);
    t = __builtin_amdgcn_update_dpp(x, x, 0x142, 0xf, 0xf, false); x = min(x, t);
    t = __builtin_amdgcn_update_dpp(x, x, 0x143, 0xf, 0xf, false); x = min(x, t);
    return (unsigned)__builtin_amdgcn_readlane((int)x, 63);
}
__device__ __forceinline__ unsigned wave_umax64(unsigned x) {
    unsigned t;
    t = __builtin_amdgcn_update_dpp(x, x, 0x111, 0xf, 0xf, false); x = max(x, t);
    t = __builtin_amdgcn_update_dpp(x, x, 0x112, 0xf, 0xf, false); x = max(x, t);
    t = __builtin_amdgcn_update_dpp(x, x, 0x114, 0xf, 0xf, false); x = max(x, t);
    t = __builtin_amdgcn_update_dpp(x, x, 0x118, 0xf, 0xf, false); x = max(x, t);
    t = __builtin_amdgcn_update_dpp(x, x, 0x142, 0xf, 0xf, false); x = max(x, t);
    t = __builtin_amdgcn_update_dpp(x, x, 0x143, 0xf, 0xf, false); x = max(x, t);
    return (unsigned)__builtin_amdgcn_readlane((int)x, 63);
}
// 8-lane butterfly sum (groups = lanes 8g..8g+7); result in all lanes of group
__device__ __forceinline__ float group8_fadd(float x) {
    float t;
    t = __int_as_float(__builtin_amdgcn_update_dpp(__float_as_int(x), __float_as_int(x), 0x0B1, 0xf, 0xf, false)); x += t; // quad_perm [1,0,3,2]
    t = __int_as_float(__builtin_amdgcn_update_dpp(__float_as_int(x), __float_as_int(x), 0x04E, 0xf, 0xf, false)); x += t; // quad_perm [2,3,0,1]
    x += __shfl_xor(x, 4, 64);
    return x;
}

__device__ __forceinline__ void norm_to(const float v[3], float o[3]) {
    float n = sqrtf(v[0]*v[0] + v[1]*v[1] + v[2]*v[2]);
    n = fmaxf(n, 1e-12f);
    o[0] = v[0]/n; o[1] = v[1]/n; o[2] = v[2]/n;
}
__device__ __forceinline__ void unit_diff(const float a[3], const float b[3], float o[3]) {
    float v[3] = {a[0]-b[0], a[1]-b[1], a[2]-b[2]};
    norm_to(v, o);
}
__device__ __forceinline__ void cross_unit(const float a[3], const float b[3], float o[3]) {
    float c[3] = {a[1]*b[2]-a[2]*b[1], a[2]*b[0]-a[0]*b[2], a[0]*b[1]-a[1]*b[0]};
    norm_to(c, o);
}

// ---------------- kernel 0a: We (400x128 f32) -> Wb fragment-major bf16 in ws ----------------
__global__ __launch_bounds__(128) void wb_prep_kernel(
    const float* __restrict__ We, unsigned short* __restrict__ Wb)
{
    const int s = blockIdx.x;          // 0..12
    const int j = threadIdx.x;         // 0..127
    unsigned* dst = (unsigned*)(Wb + ((size_t)(s*128 + j) << 5));
    #pragma unroll
    for (int m = 0; m < 16; ++m) {
        const int k0 = s*32 + 2*m;
        const unsigned lo = (k0   < 400) ? f2bu(We[(size_t)k0*128 + j])     : 0u;
        const unsigned hi = (k0+1 < 400) ? f2bu(We[(size_t)(k0+1)*128 + j]) : 0u;
        dst[m] = (hi << 16) | lo;
    }
}

// ---------------- kernel 0b: RBF lookup table: 4096 x 16 bf16 (d = idx*0.02) ----------------
__global__ __launch_bounds__(256) void rbf_tab_kernel(unsigned* __restrict__ tab)
{
    const int idx = blockIdx.x*256 + threadIdx.x;   // 0..4095
    const float t1 = (idx * 0.02f) * 0.96089935f;
    unsigned* dst = tab + ((size_t)idx << 3);
    #pragma unroll
    for (int m = 0; m < 8; ++m) {
        const float z0 = t1 - c_muS[2*m];
        const float z1 = t1 - c_muS[2*m+1];
        const float v0 = exp2f(-z0*z0);
        const float v1 = exp2f(-z1*z1);
        unsigned pk;
        asm("v_cvt_pk_bf16_f32 %0, %1, %2" : "=v"(pk) : "v"(v0), "v"(v1));
        dst[m] = pk;
    }
}

// ---------------- kernel 1: node features (V) + bb + Ca float4 pack ----------------
__global__ __launch_bounds__(128) void node_bb_kernel(
    const float* __restrict__ X, const float* __restrict__ Wn,
    const float* __restrict__ gn, const float* __restrict__ bn,
    float* __restrict__ out, float4* __restrict__ ca4)
{
    const int blk = blockIdx.x;
    const int b = blk >> 10, i = blk & 1023;
    const int tid = threadIdx.x;
    __shared__ float ang[3];
    __shared__ float red[128];

    if (tid < 3) {
        const int m = 3*i + tid;
        float dang = 0.f;
        if (m >= 1 && m <= 3*1024 - 3) {
            const int t = m - 1;
            float P[4][3];
            #pragma unroll
            for (int q = 0; q < 4; ++q) {
                const int s = t + q;
                const int ri = s / 3, ai = s - 3*ri;
                const float* p = X + (((size_t)b * 1024 + ri) * 5 + ai) * 3;
                P[q][0] = p[0]; P[q][1] = p[1]; P[q][2] = p[2];
            }
            float u2v[3], u1v[3], u0v[3];
            unit_diff(P[1], P[0], u2v);
            unit_diff(P[2], P[1], u1v);
            unit_diff(P[3], P[2], u0v);
            float n2v[3], n1v[3];
            cross_unit(u2v, u1v, n2v);
            cross_unit(u1v, u0v, n1v);
            float cosD = n2v[0]*n1v[0] + n2v[1]*n1v[1] + n2v[2]*n1v[2];
            cosD = fminf(fmaxf(cosD, -1.f + 1e-7f), 1.f - 1e-7f);
            float sg = u2v[0]*n1v[0] + u2v[1]*n1v[1] + u2v[2]*n1v[2];
            float s = (sg > 0.f) ? 1.f : ((sg < 0.f) ? -1.f : 0.f);
            dang = s * acosf(cosD);
        }
        ang[tid] = dang;
    }
    if (tid == 3) {
        const float* p = X + (size_t)blk * 15;
        float Nx=p[0],  Ny=p[1],  Nz=p[2];
        float Cax=p[3], Cay=p[4], Caz=p[5];
        float Cx=p[6],  Cy=p[7],  Cz=p[8];
        ca4[blk] = make_float4(Cax, Cay, Caz, 0.f);
        float v1[3] = {Cx-Cax, Cy-Cay, Cz-Caz};
        float v2[3] = {Nx-Cax, Ny-Cay, Nz-Caz};
        float e1[3]; norm_to(v1, e1);
        float dd = e1[0]*v2[0] + e1[1]*v2[1] + e1[2]*v2[2];
        float u2[3] = {v2[0]-e1[0]*dd, v2[1]-e1[1]*dd, v2[2]-e1[2]*dd};
        float e2[3]; norm_to(u2, e2);
        float e3[3] = {e1[1]*e2[2]-e1[2]*e2[1], e1[2]*e2[0]-e1[0]*e2[2], e1[0]*e2[1]-e1[1]*e2[0]};
        float* bb = out + BB_OFF + (size_t)blk * 16;
        bb[0]=e1[0]; bb[1]=e1[1]; bb[2]=e1[2];  bb[3]=Cax;
        bb[4]=e2[0]; bb[5]=e2[1]; bb[6]=e2[2];  bb[7]=Cay;
        bb[8]=e3[0]; bb[9]=e3[1]; bb[10]=e3[2]; bb[11]=Caz;
        bb[12]=0.f; bb[13]=0.f; bb[14]=0.f; bb[15]=0.f;
    }
    __syncthreads();
    const float a0 = ang[0], a1 = ang[1], a2 = ang[2];
    float feat[6] = {cosf(a0), cosf(a1), cosf(a2), sinf(a0), sinf(a1), sinf(a2)};
    float x = 0.f;
    #pragma unroll
    for (int f = 0; f < 6; ++f) x += feat[f] * Wn[f*128 + tid];
    red[tid] = x; __syncthreads();
    for (int s = 64; s > 0; s >>= 1) { if (tid < s) red[tid] += red[tid+s]; __syncthreads(); }
    const float mean = red[0] * (1.f/128.f);
    __syncthreads();
    const float xm = x - mean;
    red[tid] = xm*xm; __syncthreads();
    for (int s = 64; s > 0; s >>= 1) { if (tid < s) red[tid] += red[tid+s]; __syncthreads(); }
    const float var = red[0] * (1.f/128.f);
    const float y = xm / __fsqrt_rn(var + 1e-5f) * gn[tid] + bn[tid];
    out[V_OFF + (size_t)blk * 128 + tid] = y;
}

// ---------------- kernel 2: fused top-k + edge features ----------------
__global__ __launch_bounds__(256, 8) void topk_edge_kernel(
    const float* __restrict__ X, const float* __restrict__ mask,
    const unsigned short* __restrict__ Wb, const float* __restrict__ Wp,
    const float* __restrict__ bp, const float* __restrict__ ge,
    const float* __restrict__ be, const float4* __restrict__ ca4,
    const unsigned* __restrict__ rtab, float* __restrict__ out)
{
    const int blk = blockIdx.x;
    const int b = blk >> 10, i = blk & 1023;
    const int tid = threadIdx.x;
    const int w = tid >> 6, lane = tid & 63;

    __shared__ __align__(16) unsigned char uni_raw[K * SSTR * 4];  // 15840 B: A-half / S union
    __shared__ unsigned long long wl[4][K];
    __shared__ float redf4[4];
    __shared__ float nbA[K][15];
    __shared__ int   nj[K];
    __shared__ float dnbv[K];
    unsigned short* A_lds = (unsigned short*)uni_raw;
    float* S = (float*)uni_raw;

    // ---- phase 1: masked distances (coalesced float4 Ca) ----
    const float4 me = ca4[(b << 10) + i];
    const float mi  = mask[(b << 10) + i];

    float dv_r[4], m2_r[4];
    float lmax = -1.f;
    #pragma unroll
    for (int m = 0; m < 4; ++m) {
        const int j = tid + (m << 8);
        const float4 cj = ca4[(b << 10) + j];
        const float dx = __fsub_rn(me.x, cj.x);
        const float dy = __fsub_rn(me.y, cj.y);
        const float dz = __fsub_rn(me.z, cj.z);
        // numpy association order: ((dx^2+dy^2)+dz^2)+1e-6
        const float ss = __fadd_rn(__fadd_rn(__fmul_rn(dx,dx), __fmul_rn(dy,dy)), __fmul_rn(dz,dz));
        const float dist = __fsqrt_rn(__fadd_rn(ss, 1e-6f));
        const float m2 = __fmul_rn(mi, mask[(b << 10) + j]);
        const float Dv = __fmul_rn(m2, dist);
        dv_r[m] = Dv; m2_r[m] = m2;
        lmax = fmaxf(lmax, Dv);
    }
    const float wmax = __uint_as_float(wave_umax64(__float_as_uint(lmax)));
    if (lane == 0) redf4[w] = wmax;
    __syncthreads();
    const float Dmax = fmaxf(fmaxf(redf4[0], redf4[1]), fmaxf(redf4[2], redf4[3]));

    unsigned va[4];
    #pragma unroll
    for (int m = 0; m < 4; ++m)
        va[m] = __float_as_uint(__fadd_rn(dv_r[m], __fmul_rn(__fsub_rn(1.f, m2_r[m]), Dmax)));

    // ---- per-wave local top-30: DPP u32-min butterfly + ballot winner (exact) ----
    for (int k = 0; k < K; ++k) {
        const unsigned head = min(min(va[0], va[1]), min(va[2], va[3]));
        const unsigned v = wave_umin64(head);
        const int bm = (va[0] == v) ? 0 : (va[1] == v) ? 1 : (va[2] == v) ? 2 : 3;
        const unsigned jc = ((unsigned)bm << 8) | (unsigned)tid;
        const unsigned long long msk = __ballot(head == v);
        unsigned jw;
        if (__popcll(msk) == 1) {
            const int winner = (int)(__ffsll((long long)msk) - 1);
            jw = (unsigned)__builtin_amdgcn_readlane((int)jc, winner);
            if (lane == winner) {
                va[0] = (bm == 0) ? 0xffffffffu : va[0];
                va[1] = (bm == 1) ? 0xffffffffu : va[1];
                va[2] = (bm == 2) ? 0xffffffffu : va[2];
                va[3] = (bm == 3) ? 0xffffffffu : va[3];
            }
        } else {
            jw = wave_umin64((head == v) ? jc : 0xffffffffu);
            if (head == v && jc == jw) {
                va[0] = (bm == 0) ? 0xffffffffu : va[0];
                va[1] = (bm == 1) ? 0xffffffffu : va[1];
                va[2] = (bm == 2) ? 0xffffffffu : va[2];
                va[3] = (bm == 3) ? 0xffffffffu : va[3];
            }
        }
        if (lane == 0) wl[w][k] = ((unsigned long long)v << 32) | jw;
    }
    __syncthreads();

    // ---- 4-way merge of sorted lists (wave 0) ----
    if (w == 0) {
        int h0 = 0, h1 = 0, h2 = 0, h3 = 0;
        for (int k = 0; k < K; ++k) {
            const unsigned long long c0 = wl[0][h0], c1 = wl[1][h1];
            const unsigned long long c2 = wl[2][h2], c3 = wl[3][h3];
            unsigned long long mb = c0 < c1 ? c0 : c1;
            const unsigned long long m23 = c2 < c3 ? c2 : c3;
            mb = mb < m23 ? mb : m23;
            if (lane == 0) {
                const int j = (int)(mb & 0xffffffffu);
                nj[k] = j;
                dnbv[k] = __uint_as_float((unsigned)(mb >> 32));
                out[EIDX_OFF + (size_t)blk * K + k] = (float)j;
            }
            if (mb == c0) ++h0; else if (mb == c1) ++h1; else if (mb == c2) ++h2; else ++h3;
        }
    }
    __syncthreads();

    // ---- fetch neighbor atoms ----
    for (int t = tid; t < K*15; t += 256) {
        const int e = t / 15, r = t - e*15;
        nbA[e][r] = X[((size_t)(b << 10) + nj[e])*15 + r];
    }
    __syncthreads();

    const float* sa = X + (size_t)blk * 15;
    f32x4 acc00 = {0,0,0,0}, acc01 = {0,0,0,0}, acc10 = {0,0,0,0}, acc11 = {0,0,0,0};
    const int ar = lane & 15;
    const int kg = (lane >> 4) * 8;
    const unsigned short* a_base = A_lds + ar*AH + kg;
    const unsigned short* a_base1 = a_base + 16*AH;
    const unsigned short* b_base = Wb + ((size_t)(w*32 + ar) << 5) + kg;

    // ================= PASS 1: g in [0,12), k-global [0,192) =================
    for (int t = tid; t < K*12; t += 256) {
        const int e = t / 12, g = t - e*12;
        float d;
        if (g == 0) d = dnbv[e];
        else {
            const int p = g - 1;
            const int aA = c_pairA[p], aB = c_pairB[p];
            const float dx = sa[aA*3+0] - nbA[e][aB*3+0];
            const float dy = sa[aA*3+1] - nbA[e][aB*3+1];
            const float dz = sa[aA*3+2] - nbA[e][aB*3+2];
            d = sqrtf(dx*dx + dy*dy + dz*dz + 1e-6f);
        }
        int idx = (int)__fmaf_rn(d, 50.f, 0.5f);
        idx = min(idx, 4095);
        const uint4* src = (const uint4*)(rtab + ((size_t)idx << 3));
        uint4* dst = (uint4*)(A_lds + e*AH + g*NRBF);
        dst[0] = src[0]; dst[1] = src[1];
    }
    __syncthreads();
    #pragma unroll
    for (int s = 0; s < 6; ++s) {
        const bf16x8 a0 = *reinterpret_cast<const bf16x8*>(a_base + s*32);
        const bf16x8 a1 = *reinterpret_cast<const bf16x8*>(a_base1 + s*32);
        const bf16x8 b0 = *reinterpret_cast<const bf16x8*>(b_base + (size_t)s*4096);
        const bf16x8 b1 = *reinterpret_cast<const bf16x8*>(b_base + (size_t)s*4096 + 512);
        acc00 = __builtin_amdgcn_mfma_f32_16x16x32_bf16(a0, b0, acc00, 0, 0, 0);
        acc01 = __builtin_amdgcn_mfma_f32_16x16x32_bf16(a0, b1, acc01, 0, 0, 0);
        acc10 = __builtin_amdgcn_mfma_f32_16x16x32_bf16(a1, b0, acc10, 0, 0, 0);
        acc11 = __builtin_amdgcn_mfma_f32_16x16x32_bf16(a1, b1, acc11, 0, 0, 0);
    }
    __syncthreads();   // pass-1 A reads complete

    // ================= PASS 2: g in [12,25), k-global [192,400)+pad =================
    for (int t = tid; t < K*13; t += 256) {
        const int e = t / 13, gg = t - e*13;
        const int p = 11 + gg;
        const int aA = c_pairA[p], aB = c_pairB[p];
        const float dx = sa[aA*3+0] - nbA[e][aB*3+0];
        const float dy = sa[aA*3+1] - nbA[e][aB*3+1];
        const float dz = sa[aA*3+2] - nbA[e][aB*3+2];
        const float d = sqrtf(dx*dx + dy*dy + dz*dz + 1e-6f);
        int idx = (int)__fmaf_rn(d, 50.f, 0.5f);
        idx = min(idx, 4095);
        const uint4* src = (const uint4*)(rtab + ((size_t)idx << 3));
        uint4* dst = (uint4*)(A_lds + e*AH + gg*NRBF);
        dst[0] = src[0]; dst[1] = src[1];
    }
    // zero k-local pad [208,224) for data rows 0..29
    for (int t = tid; t < K*8; t += 256) {
        const int e = t >> 3, c = t & 7;
        ((unsigned*)(A_lds + e*AH + 208))[c] = 0u;
    }
    __syncthreads();
    #pragma unroll
    for (int s = 0; s < 7; ++s) {
        const bf16x8 a0 = *reinterpret_cast<const bf16x8*>(a_base + s*32);
        const bf16x8 a1 = *reinterpret_cast<const bf16x8*>(a_base1 + s*32);
        const bf16x8 b0 = *reinterpret_cast<const bf16x8*>(b_base + (size_t)(6+s)*4096);
        const bf16x8 b1 = *reinterpret_cast<const bf16x8*>(b_base + (size_t)(6+s)*4096 + 512);
        acc00 = __builtin_amdgcn_mfma_f32_16x16x32_bf16(a0, b0, acc00, 0, 0, 0);
        acc01 = __builtin_amdgcn_mfma_f32_16x16x32_bf16(a0, b1, acc01, 0, 0, 0);
        acc10 = __builtin_amdgcn_mfma_f32_16x16x32_bf16(a1, b0, acc10, 0, 0, 0);
        acc11 = __builtin_amdgcn_mfma_f32_16x16x32_bf16(a1, b1, acc11, 0, 0, 0);
    }
    __syncthreads();   // pass-2 A reads complete; union region becomes S

    {
        // C layout (m89): col = lane&15, row = (lane>>4)*4 + reg
        const int crow = (lane >> 4) * 4;
        const int ccol = w*32 + (lane & 15);
        #pragma unroll
        for (int r = 0; r < 4; ++r) {
            const int r0 = crow + r;
            if (r0 < K) { S[r0*SSTR + ccol] = acc00[r]; S[r0*SSTR + ccol + 16] = acc01[r]; }
            const int r1 = 16 + crow + r;
            if (r1 < K) { S[r1*SSTR + ccol] = acc10[r]; S[r1*SSTR + ccol + 16] = acc11[r]; }
        }
    }
    __syncthreads();

    // ---- positional embedding + bias (float4 items: 30 edges x 32 quads) ----
    #pragma unroll
    for (int n = 0; n < 4; ++n) {
        const int item = tid + (n << 8);
        if (item < 960) {
            const int e = item >> 5, q = item & 31;
            int off = i - nj[e] + 32;
            off = off < 0 ? 0 : (off > 64 ? 64 : off);
            const float4 wp = ((const float4*)(Wp + (size_t)off*128))[q];
            const float4 bq = ((const float4*)bp)[q];
            float4* sp = (float4*)(S + e*SSTR) + q;
            float4 sv = *sp;
            sv.x += wp.x + bq.x; sv.y += wp.y + bq.y;
            sv.z += wp.z + bq.z; sv.w += wp.w + bq.w;
            *sp = sv;
        }
    }
    __syncthreads();

    // ---- per-edge LayerNorm: one thread per (edge, 16-elem strip) ----
    {
        const int e = tid >> 3, s8 = tid & 7;
        if (e < K) {
            const float* row = S + e*SSTR + s8*16;
            float xv[16];
            float sum = 0.f;
            #pragma unroll
            for (int c = 0; c < 4; ++c) {
                const float4 q = ((const float4*)row)[c];
                xv[4*c+0] = q.x; xv[4*c+1] = q.y; xv[4*c+2] = q.z; xv[4*c+3] = q.w;
                sum += q.x + q.y + q.z + q.w;
            }
            const float mean = group8_fadd(sum) * (1.f/128.f);
            float vs = 0.f;
            #pragma unroll
            for (int c = 0; c < 16; ++c) { const float d = xv[c] - mean; xv[c] = d; vs = __fmaf_rn(d, d, vs); }
            const float inv = 1.f / __fsqrt_rn(group8_fadd(vs) * (1.f/128.f) + 1e-5f);
            const int j0 = s8*16;
            float* op = out + E_OFF + ((size_t)blk * K + e) * 128 + j0;
            #pragma unroll
            for (int c = 0; c < 4; ++c) {
                const float4 g4 = ((const float4*)(ge + j0))[c];
                const float4 b4 = ((const float4*)(be + j0))[c];
                float4 o;
                o.x = xv[4*c+0] * inv * g4.x + b4.x;
                o.y = xv[4*c+1] * inv * g4.y + b4.y;
                o.z = xv[4*c+2] * inv * g4.z + b4.z;
                o.w = xv[4*c+3] * inv * g4.w + b4.w;
                ((float4*)op)[c] = o;
            }
        }
    }
}

extern "C" void kernel_launch(void* const* d_in, const int* in_sizes, int n_in,
                              void* d_out, int out_size, void* d_ws, size_t ws_size,
                              hipStream_t stream) {
    const float* X    = (const float*)d_in[0];
    const float* mask = (const float*)d_in[1];
    // d_in[2] = Lvec (int32), unused
    const float* We   = (const float*)d_in[3];
    const float* Wn   = (const float*)d_in[4];
    const float* Wp   = (const float*)d_in[5];
    const float* bp   = (const float*)d_in[6];
    const float* gE   = (const float*)d_in[7];
    const float* bE   = (const float*)d_in[8];
    const float* gN   = (const float*)d_in[9];
    const float* bN   = (const float*)d_in[10];
    float* out = (float*)d_out;
    unsigned short* Wb = (unsigned short*)d_ws;                    // 106,496 B
    float4* ca4 = (float4*)((char*)d_ws + 106496);                 // 131,072 B
    unsigned* rtab = (unsigned*)((char*)d_ws + 106496 + 131072);   // 131,072 B

    hipLaunchKernelGGL(wb_prep_kernel,   dim3(13),   dim3(128), 0, stream, We, Wb);
    hipLaunchKernelGGL(rbf_tab_kernel,   dim3(16),   dim3(256), 0, stream, rtab);
    hipLaunchKernelGGL(node_bb_kernel,   dim3(8192), dim3(128), 0, stream, X, Wn, gN, bN, out, ca4);
    hipLaunchKernelGGL(topk_edge_kernel, dim3(8192), dim3(256), 0, stream,
                       X, mask, Wb, Wp, bp, gE, bE, ca4, rtab, out);
}

// Round 10
// 157.845 us; speedup vs baseline: 7.1410x; 1.0500x over previous
//
#include <hip/hip_runtime.h>
#include <hip/hip_bf16.h>
#include <math.h>

// Outputs are FLOAT32. B=8, L=1024, K=30, F=128 -> flat offsets (f32 elements):
#define V_OFF    ((size_t)0)
#define E_OFF    ((size_t)1048576)
#define EIDX_OFF ((size_t)32505856)
#define BB_OFF   ((size_t)32751616)

#define K 30
#define NRBF 16
#define AH   232          // A-half LDS row stride in bf16
#define SSTR 132          // padded S stride (f32)

typedef __attribute__((ext_vector_type(8))) short bf16x8;
typedef __attribute__((ext_vector_type(4))) float f32x4;

// atom indices: N=0, Ca=1, C=2, CB=3, O=4
__device__ __constant__ int c_pairA[24] = {0,2,4,3,1,1,1,1,0,0,0,3,3,4,0,2,4,3,2,4,3,2,4,2};
__device__ __constant__ int c_pairB[24] = {0,2,4,3,0,2,4,3,2,4,3,2,4,2,1,1,1,1,0,0,0,3,3,4};

// mu_k * 0.8 * sqrt(log2(e)) for exp2-folded RBF
__device__ __constant__ float c_muS[16] = {
    1.92179871f, 3.20299785f, 4.48419699f, 5.76539613f, 7.04659527f, 8.32779441f,
    9.60899355f, 10.89019269f, 12.17139183f, 13.45259097f, 14.73379011f, 16.01498925f,
    17.29618839f, 18.57738753f, 19.85858667f, 21.13978581f};

__device__ __forceinline__ unsigned short f2bu(float f) {   // RNE f32->bf16 bits (finite)
    unsigned x = __float_as_uint(f);
    return (unsigned short)((x + 0x7fffu + ((x >> 16) & 1u)) >> 16);
}

// ---- DPP wave-64 reductions (result in lane 63, broadcast via readlane) ----
__device__ __forceinline__ unsigned wave_umin64(unsigned x) {
    unsigned t;
    t = __builtin_amdgcn_update_dpp(x, x, 0x111, 0xf, 0xf, false); x = min(x, t);
    t = __builtin_amdgcn_update_dpp(x, x, 0x112, 0xf, 0xf, false); x = min(x, t);
    t = __builtin_amdgcn_update_dpp(x, x, 0x114, 0xf, 0xf, false); x = min(x, t);
    t = __builtin_amdgcn_update_dpp(x, x, 0x118, 0xf, 0xf, false); x = min(x, t);
    t = __builtin_amdgcn_update_dpp(x, x, 0x142, 0xf, 0xf, false); x = min(x, t);
    t = __builtin_amdgcn_update_dpp(x, x, 0x143, 0xf, 0xf, false); x = min(x, t);
    return (unsigned)__builtin_amdgcn_readlane((int)x, 63);
}
__device__ __forceinline__ unsigned wave_umax64(unsigned x) {
    unsigned t;
    t = __builtin_amdgcn_update_dpp(x, x, 0x111, 0xf, 0xf, false); x = max(x, t);
    t = __builtin_amdgcn_update_dpp(x, x, 0x112, 0xf, 0xf, false); x = max(x, t);
    t = __builtin_amdgcn_update_dpp(x, x, 0x114, 0xf, 0xf, false); x = max(x, t);
    t = __builtin_amdgcn_update_dpp(x, x, 0x118, 0xf, 0xf, false); x = max(x, t);
    t = __builtin_amdgcn_update_dpp(x, x, 0x142, 0xf, 0xf, false); x = max(x, t);
    t = __builtin_amdgcn_update_dpp(x, x, 0x143, 0xf, 0xf, false); x = max(x, t);
    return (unsigned)__builtin_amdgcn_readlane((int)x, 63);
}
// u64 lexicographic min across 64 lanes (keys (value<<32)|index)
#define U64_STEP(ctl) { \
    const unsigned lo_ = (unsigned)x, hi_ = (unsigned)(x >> 32); \
    const unsigned plo = __builtin_amdgcn_update_dpp(lo_, lo_, ctl, 0xf, 0xf, false); \
    const unsigned phi = __builtin_amdgcn_update_dpp(hi_, hi_, ctl, 0xf, 0xf, false); \
    const unsigned long long p = ((unsigned long long)phi << 32) | plo; \
    x = p < x ? p : x; }
__device__ __forceinline__ unsigned long long wave_u64min(unsigned long long x) {
    U64_STEP(0x111) U64_STEP(0x112) U64_STEP(0x114)
    U64_STEP(0x118) U64_STEP(0x142) U64_STEP(0x143)
    const unsigned rlo = (unsigned)__builtin_amdgcn_readlane((int)(unsigned)x, 63);
    const unsigned rhi = (unsigned)__builtin_amdgcn_readlane((int)(unsigned)(x >> 32), 63);
    return ((unsigned long long)rhi << 32) | rlo;
}
__device__ __forceinline__ unsigned mbcnt64(unsigned long long m) {
    return __builtin_amdgcn_mbcnt_hi((unsigned)(m >> 32),
           __builtin_amdgcn_mbcnt_lo((unsigned)m, 0u));
}
// 8-lane butterfly sum (groups = lanes 8g..8g+7)
__device__ __forceinline__ float group8_fadd(float x) {
    float t;
    t = __int_as_float(__builtin_amdgcn_update_dpp(__float_as_int(x), __float_as_int(x), 0x0B1, 0xf, 0xf, false)); x += t;
    t = __int_as_float(__builtin_amdgcn_update_dpp(__float_as_int(x), __float_as_int(x), 0x04E, 0xf, 0xf, false)); x += t;
    x += __shfl_xor(x, 4, 64);
    return x;
}

__device__ __forceinline__ void norm_to(const float v[3], float o[3]) {
    float n = sqrtf(v[0]*v[0] + v[1]*v[1] + v[2]*v[2]);
    n = fmaxf(n, 1e-12f);
    o[0] = v[0]/n; o[1] = v[1]/n; o[2] = v[2]/n;
}
__device__ __forceinline__ void unit_diff(const float a[3], const float b[3], float o[3]) {
    float v[3] = {a[0]-b[0], a[1]-b[1], a[2]-b[2]};
    norm_to(v, o);
}
__device__ __forceinline__ void cross_unit(const float a[3], const float b[3], float o[3]) {
    float c[3] = {a[1]*b[2]-a[2]*b[1], a[2]*b[0]-a[0]*b[2], a[0]*b[1]-a[1]*b[0]};
    norm_to(c, o);
}

// ---------------- kernel 0a: We (400x128 f32) -> Wb fragment-major bf16 in ws ----------------
__global__ __launch_bounds__(128) void wb_prep_kernel(
    const float* __restrict__ We, unsigned short* __restrict__ Wb)
{
    const int s = blockIdx.x;          // 0..12
    const int j = threadIdx.x;         // 0..127
    unsigned* dst = (unsigned*)(Wb + ((size_t)(s*128 + j) << 5));
    #pragma unroll
    for (int m = 0; m < 16; ++m) {
        const int k0 = s*32 + 2*m;
        const unsigned lo = (k0   < 400) ? f2bu(We[(size_t)k0*128 + j])     : 0u;
        const unsigned hi = (k0+1 < 400) ? f2bu(We[(size_t)(k0+1)*128 + j]) : 0u;
        dst[m] = (hi << 16) | lo;
    }
}

// ---------------- kernel 0b: RBF lookup table: 4096 x 16 bf16 (d = idx*0.02) ----------------
__global__ __launch_bounds__(256) void rbf_tab_kernel(unsigned* __restrict__ tab)
{
    const int idx = blockIdx.x*256 + threadIdx.x;   // 0..4095
    const float t1 = (idx * 0.02f) * 0.96089935f;
    unsigned* dst = tab + ((size_t)idx << 3);
    #pragma unroll
    for (int m = 0; m < 8; ++m) {
        const float z0 = t1 - c_muS[2*m];
        const float z1 = t1 - c_muS[2*m+1];
        const float v0 = exp2f(-z0*z0);
        const float v1 = exp2f(-z1*z1);
        unsigned pk;
        asm("v_cvt_pk_bf16_f32 %0, %1, %2" : "=v"(pk) : "v"(v0), "v"(v1));
        dst[m] = pk;
    }
}

// ---------------- kernel 1: node features (V) + bb + Ca float4 pack ----------------
__global__ __launch_bounds__(128) void node_bb_kernel(
    const float* __restrict__ X, const float* __restrict__ Wn,
    const float* __restrict__ gn, const float* __restrict__ bn,
    float* __restrict__ out, float4* __restrict__ ca4)
{
    const int blk = blockIdx.x;
    const int b = blk >> 10, i = blk & 1023;
    const int tid = threadIdx.x;
    __shared__ float ang[3];
    __shared__ float red[128];

    if (tid < 3) {
        const int m = 3*i + tid;
        float dang = 0.f;
        if (m >= 1 && m <= 3*1024 - 3) {
            const int t = m - 1;
            float P[4][3];
            #pragma unroll
            for (int q = 0; q < 4; ++q) {
                const int s = t + q;
                const int ri = s / 3, ai = s - 3*ri;
                const float* p = X + (((size_t)b * 1024 + ri) * 5 + ai) * 3;
                P[q][0] = p[0]; P[q][1] = p[1]; P[q][2] = p[2];
            }
            float u2v[3], u1v[3], u0v[3];
            unit_diff(P[1], P[0], u2v);
            unit_diff(P[2], P[1], u1v);
            unit_diff(P[3], P[2], u0v);
            float n2v[3], n1v[3];
            cross_unit(u2v, u1v, n2v);
            cross_unit(u1v, u0v, n1v);
            float cosD = n2v[0]*n1v[0] + n2v[1]*n1v[1] + n2v[2]*n1v[2];
            cosD = fminf(fmaxf(cosD, -1.f + 1e-7f), 1.f - 1e-7f);
            float sg = u2v[0]*n1v[0] + u2v[1]*n1v[1] + u2v[2]*n1v[2];
            float s = (sg > 0.f) ? 1.f : ((sg < 0.f) ? -1.f : 0.f);
            dang = s * acosf(cosD);
        }
        ang[tid] = dang;
    }
    if (tid == 3) {
        const float* p = X + (size_t)blk * 15;
        float Nx=p[0],  Ny=p[1],  Nz=p[2];
        float Cax=p[3], Cay=p[4], Caz=p[5];
        float Cx=p[6],  Cy=p[7],  Cz=p[8];
        ca4[blk] = make_float4(Cax, Cay, Caz, 0.f);
        float v1[3] = {Cx-Cax, Cy-Cay, Cz-Caz};
        float v2[3] = {Nx-Cax, Ny-Cay, Nz-Caz};
        float e1[3]; norm_to(v1, e1);
        float dd = e1[0]*v2[0] + e1[1]*v2[1] + e1[2]*v2[2];
        float u2[3] = {v2[0]-e1[0]*dd, v2[1]-e1[1]*dd, v2[2]-e1[2]*dd};
        float e2[3]; norm_to(u2, e2);
        float e3[3] = {e1[1]*e2[2]-e1[2]*e2[1], e1[2]*e2[0]-e1[0]*e2[2], e1[0]*e2[1]-e1[1]*e2[0]};
        float* bb = out + BB_OFF + (size_t)blk * 16;
        bb[0]=e1[0]; bb[1]=e1[1]; bb[2]=e1[2];  bb[3]=Cax;
        bb[4]=e2[0]; bb[5]=e2[1]; bb[6]=e2[2];  bb[7]=Cay;
        bb[8]=e3[0]; bb[9]=e3[1]; bb[10]=e3[2]; bb[11]=Caz;
        bb[12]=0.f; bb[13]=0.f; bb[14]=0.f; bb[15]=0.f;
    }
    __syncthreads();
    const float a0 = ang[0], a1 = ang[1], a2 = ang[2];
    float feat[6] = {cosf(a0), cosf(a1), cosf(a2), sinf(a0), sinf(a1), sinf(a2)};
    float x = 0.f;
    #pragma unroll
    for (int f = 0; f < 6; ++f) x += feat[f] * Wn[f*128 + tid];
    red[tid] = x; __syncthreads();
    for (int s = 64; s > 0; s >>= 1) { if (tid < s) red[tid] += red[tid+s]; __syncthreads(); }
    const float mean = red[0] * (1.f/128.f);
    __syncthreads();
    const float xm = x - mean;
    red[tid] = xm*xm; __syncthreads();
    for (int s = 64; s > 0; s >>= 1) { if (tid < s) red[tid] += red[tid+s]; __syncthreads(); }
    const float var = red[0] * (1.f/128.f);
    const float y = xm / __fsqrt_rn(var + 1e-5f) * gn[tid] + bn[tid];
    out[V_OFF + (size_t)blk * 128 + tid] = y;
}

// ---------------- kernel 2: fused top-k + edge features ----------------
__global__ __launch_bounds__(256, 8) void topk_edge_kernel(
    const float* __restrict__ X, const float* __restrict__ mask,
    const unsigned short* __restrict__ Wb, const float* __restrict__ Wp,
    const float* __restrict__ bp, const float* __restrict__ ge,
    const float* __restrict__ be, const float4* __restrict__ ca4,
    const unsigned* __restrict__ rtab, float* __restrict__ out)
{
    const int blk = blockIdx.x;
    const int b = blk >> 10, i = blk & 1023;
    const int tid = threadIdx.x;
    const int w = tid >> 6, lane = tid & 63;

    __shared__ __align__(16) unsigned char uni_raw[K * SSTR * 4];  // 15840 B: surv / A-half / S union
    __shared__ float redf4[4];
    __shared__ unsigned redT[4];
    __shared__ int   scount;
    __shared__ float nbA[K][15];
    __shared__ int   nj[K];
    __shared__ float dnbv[K];
    unsigned short* A_lds = (unsigned short*)uni_raw;
    float* S = (float*)uni_raw;
    unsigned long long* surv = (unsigned long long*)uni_raw;   // phase-1 only (<= 8192 B)

    if (tid == 0) scount = 0;

    // ---- phase 1: masked distances (coalesced float4 Ca) ----
    const float4 me = ca4[(b << 10) + i];
    const float mi  = mask[(b << 10) + i];

    float dv_r[4], m2_r[4];
    float lmax = -1.f;
    #pragma unroll
    for (int m = 0; m < 4; ++m) {
        const int j = tid + (m << 8);
        const float4 cj = ca4[(b << 10) + j];
        const float dx = __fsub_rn(me.x, cj.x);
        const float dy = __fsub_rn(me.y, cj.y);
        const float dz = __fsub_rn(me.z, cj.z);
        // numpy association order: ((dx^2+dy^2)+dz^2)+1e-6
        const float ss = __fadd_rn(__fadd_rn(__fmul_rn(dx,dx), __fmul_rn(dy,dy)), __fmul_rn(dz,dz));
        const float dist = __fsqrt_rn(__fadd_rn(ss, 1e-6f));
        const float m2 = __fmul_rn(mi, mask[(b << 10) + j]);
        const float Dv = __fmul_rn(m2, dist);
        dv_r[m] = Dv; m2_r[m] = m2;
        lmax = fmaxf(lmax, Dv);
    }
    const float wmax = __uint_as_float(wave_umax64(__float_as_uint(lmax)));
    if (lane == 0) redf4[w] = wmax;
    __syncthreads();           // also covers scount init
    const float Dmax = fmaxf(fmaxf(redf4[0], redf4[1]), fmaxf(redf4[2], redf4[3]));

    unsigned va[4];
    #pragma unroll
    for (int m = 0; m < 4; ++m)
        va[m] = __float_as_uint(__fadd_rn(dv_r[m], __fmul_rn(__fsub_rn(1.f, m2_r[m]), Dmax)));

    // ---- Step A: per-wave value-only top-8 -> threshold Tw (no index tracking) ----
    {
        unsigned vb0 = va[0], vb1 = va[1], vb2 = va[2], vb3 = va[3];
        unsigned v = 0;
        #pragma unroll
        for (int k = 0; k < 8; ++k) {
            const unsigned head = min(min(vb0, vb1), min(vb2, vb3));
            v = wave_umin64(head);
            vb0 = (vb0 == v) ? 0xffffffffu : vb0;
            vb1 = (vb1 == v) ? 0xffffffffu : vb1;
            vb2 = (vb2 == v) ? 0xffffffffu : vb2;
            vb3 = (vb3 == v) ? 0xffffffffu : vb3;
        }
        if (lane == 0) redT[w] = v;
    }
    __syncthreads();
    // T = max of wave thresholds: >= 32 candidates have value <= T, so top-30 all survive.
    const unsigned T = max(max(redT[0], redT[1]), max(redT[2], redT[3]));

    // ---- Step B: compact survivors (value<<32|index) into LDS ----
    {
        unsigned long long mm0 = __ballot(va[0] <= T);
        unsigned long long mm1 = __ballot(va[1] <= T);
        unsigned long long mm2 = __ballot(va[2] <= T);
        unsigned long long mm3 = __ballot(va[3] <= T);
        const unsigned c0 = __popcll(mm0), c1 = __popcll(mm1);
        const unsigned c2 = __popcll(mm2), c3 = __popcll(mm3);
        int old = 0;
        if (lane == 0) old = atomicAdd(&scount, (int)(c0 + c1 + c2 + c3));
        unsigned base = (unsigned)__builtin_amdgcn_readfirstlane(old);
        if (va[0] <= T) surv[base + mbcnt64(mm0)] = ((unsigned long long)va[0] << 32) | (unsigned)tid;
        base += c0;
        if (va[1] <= T) surv[base + mbcnt64(mm1)] = ((unsigned long long)va[1] << 32) | (unsigned)(tid + 256);
        base += c1;
        if (va[2] <= T) surv[base + mbcnt64(mm2)] = ((unsigned long long)va[2] << 32) | (unsigned)(tid + 512);
        base += c2;
        if (va[3] <= T) surv[base + mbcnt64(mm3)] = ((unsigned long long)va[3] << 32) | (unsigned)(tid + 768);
    }
    __syncthreads();
    const int N = scount;

    // ---- Step C: wave 0 extracts exact top-30 by u64 key (value, index) ----
    if (w == 0) {
        if (N <= 128) {
            unsigned long long k0 = (lane < N) ? surv[lane] : ~0ull;
            unsigned long long k1 = (lane + 64 < N) ? surv[lane + 64] : ~0ull;
            for (int k = 0; k < K; ++k) {
                const unsigned long long h = k0 < k1 ? k0 : k1;
                const unsigned long long best = wave_u64min(h);
                k0 = (k0 == best) ? ~0ull : k0;   // keys unique -> exactly one removal
                k1 = (k1 == best) ? ~0ull : k1;
                if (lane == 0) {
                    const int j = (int)(best & 0xffffffffu);
                    nj[k] = j;
                    dnbv[k] = __uint_as_float((unsigned)(best >> 32));
                    out[EIDX_OFF + (size_t)blk * K + k] = (float)j;
                }
            }
        } else {
            for (int k = 0; k < K; ++k) {
                unsigned long long h = ~0ull;
                for (int t = lane; t < N; t += 64) { const unsigned long long c = surv[t]; h = c < h ? c : h; }
                const unsigned long long best = wave_u64min(h);
                for (int t = lane; t < N; t += 64) if (surv[t] == best) surv[t] = ~0ull;
                if (lane == 0) {
                    const int j = (int)(best & 0xffffffffu);
                    nj[k] = j;
                    dnbv[k] = __uint_as_float((unsigned)(best >> 32));
                    out[EIDX_OFF + (size_t)blk * K + k] = (float)j;
                }
            }
        }
    }
    __syncthreads();

    // ---- fetch neighbor atoms ----
    for (int t = tid; t < K*15; t += 256) {
        const int e = t / 15, r = t - e*15;
        nbA[e][r] = X[((size_t)(b << 10) + nj[e])*15 + r];
    }
    __syncthreads();

    const float* sa = X + (size_t)blk * 15;
    f32x4 acc00 = {0,0,0,0}, acc01 = {0,0,0,0}, acc10 = {0,0,0,0}, acc11 = {0,0,0,0};
    const int ar = lane & 15;
    const int kg = (lane >> 4) * 8;
    const unsigned short* a_base = A_lds + ar*AH + kg;
    const unsigned short* a_base1 = a_base + 16*AH;
    const unsigned short* b_base = Wb + ((size_t)(w*32 + ar) << 5) + kg;

    // ================= PASS 1: g in [0,12), k-global [0,192) =================
    for (int t = tid; t < K*12; t += 256) {
        const int e = t / 12, g = t - e*12;
        float d;
        if (g == 0) d = dnbv[e];
        else {
            const int p = g - 1;
            const int aA = c_pairA[p], aB = c_pairB[p];
            const float dx = sa[aA*3+0] - nbA[e][aB*3+0];
            const float dy = sa[aA*3+1] - nbA[e][aB*3+1];
            const float dz = sa[aA*3+2] - nbA[e][aB*3+2];
            d = sqrtf(dx*dx + dy*dy + dz*dz + 1e-6f);
        }
        int idx = (int)__fmaf_rn(d, 50.f, 0.5f);
        idx = min(idx, 4095);
        const uint4* src = (const uint4*)(rtab + ((size_t)idx << 3));
        uint4* dst = (uint4*)(A_lds + e*AH + g*NRBF);
        dst[0] = src[0]; dst[1] = src[1];
    }
    __syncthreads();
    #pragma unroll
    for (int s = 0; s < 6; ++s) {
        const bf16x8 a0 = *reinterpret_cast<const bf16x8*>(a_base + s*32);
        const bf16x8 a1 = *reinterpret_cast<const bf16x8*>(a_base1 + s*32);
        const bf16x8 b0 = *reinterpret_cast<const bf16x8*>(b_base + (size_t)s*4096);
        const bf16x8 b1 = *reinterpret_cast<const bf16x8*>(b_base + (size_t)s*4096 + 512);
        acc00 = __builtin_amdgcn_mfma_f32_16x16x32_bf16(a0, b0, acc00, 0, 0, 0);
        acc01 = __builtin_amdgcn_mfma_f32_16x16x32_bf16(a0, b1, acc01, 0, 0, 0);
        acc10 = __builtin_amdgcn_mfma_f32_16x16x32_bf16(a1, b0, acc10, 0, 0, 0);
        acc11 = __builtin_amdgcn_mfma_f32_16x16x32_bf16(a1, b1, acc11, 0, 0, 0);
    }
    __syncthreads();   // pass-1 A reads complete

    // ================= PASS 2: g in [12,25), k-global [192,400)+pad =================
    for (int t = tid; t < K*13; t += 256) {
        const int e = t / 13, gg = t - e*13;
        const int p = 11 + gg;
        const int aA = c_pairA[p], aB = c_pairB[p];
        const float dx = sa[aA*3+0] - nbA[e][aB*3+0];
        const float dy = sa[aA*3+1] - nbA[e][aB*3+1];
        const float dz = sa[aA*3+2] - nbA[e][aB*3+2];
        const float d = sqrtf(dx*dx + dy*dy + dz*dz + 1e-6f);
        int idx = (int)__fmaf_rn(d, 50.f, 0.5f);
        idx = min(idx, 4095);
        const uint4* src = (const uint4*)(rtab + ((size_t)idx << 3));
        uint4* dst = (uint4*)(A_lds + e*AH + gg*NRBF);
        dst[0] = src[0]; dst[1] = src[1];
    }
    // zero k-local pad [208,224) for data rows 0..29
    for (int t = tid; t < K*8; t += 256) {
        const int e = t >> 3, c = t & 7;
        ((unsigned*)(A_lds + e*AH + 208))[c] = 0u;
    }
    __syncthreads();
    #pragma unroll
    for (int s = 0; s < 7; ++s) {
        const bf16x8 a0 = *reinterpret_cast<const bf16x8*>(a_base + s*32);
        const bf16x8 a1 = *reinterpret_cast<const bf16x8*>(a_base1 + s*32);
        const bf16x8 b0 = *reinterpret_cast<const bf16x8*>(b_base + (size_t)(6+s)*4096);
        const bf16x8 b1 = *reinterpret_cast<const bf16x8*>(b_base + (size_t)(6+s)*4096 + 512);
        acc00 = __builtin_amdgcn_mfma_f32_16x16x32_bf16(a0, b0, acc00, 0, 0, 0);
        acc01 = __builtin_amdgcn_mfma_f32_16x16x32_bf16(a0, b1, acc01, 0, 0, 0);
        acc10 = __builtin_amdgcn_mfma_f32_16x16x32_bf16(a1, b0, acc10, 0, 0, 0);
        acc11 = __builtin_amdgcn_mfma_f32_16x16x32_bf16(a1, b1, acc11, 0, 0, 0);
    }
    __syncthreads();   // pass-2 A reads complete; union region becomes S

    {
        // C layout (m89): col = lane&15, row = (lane>>4)*4 + reg
        const int crow = (lane >> 4) * 4;
        const int ccol = w*32 + (lane & 15);
        #pragma unroll
        for (int r = 0; r < 4; ++r) {
            const int r0 = crow + r;
            if (r0 < K) { S[r0*SSTR + ccol] = acc00[r]; S[r0*SSTR + ccol + 16] = acc01[r]; }
            const int r1 = 16 + crow + r;
            if (r1 < K) { S[r1*SSTR + ccol] = acc10[r]; S[r1*SSTR + ccol + 16] = acc11[r]; }
        }
    }
    __syncthreads();

    // ---- positional embedding + bias (float4 items: 30 edges x 32 quads) ----
    #pragma unroll
    for (int n = 0; n < 4; ++n) {
        const int item = tid + (n << 8);
        if (item < 960) {
            const int e = item >> 5, q = item & 31;
            int off = i - nj[e] + 32;
            off = off < 0 ? 0 : (off > 64 ? 64 : off);
            const float4 wp = ((const float4*)(Wp + (size_t)off*128))[q];
            const float4 bq = ((const float4*)bp)[q];
            float4* sp = (float4*)(S + e*SSTR) + q;
            float4 sv = *sp;
            sv.x += wp.x + bq.x; sv.y += wp.y + bq.y;
            sv.z += wp.z + bq.z; sv.w += wp.w + bq.w;
            *sp = sv;
        }
    }
    __syncthreads();

    // ---- per-edge LayerNorm: one thread per (edge, 16-elem strip) ----
    {
        const int e = tid >> 3, s8 = tid & 7;
        if (e < K) {
            const float* row = S + e*SSTR + s8*16;
            float xv[16];
            float sum = 0.f;
            #pragma unroll
            for (int c = 0; c < 4; ++c) {
                const float4 q = ((const float4*)row)[c];
                xv[4*c+0] = q.x; xv[4*c+1] = q.y; xv[4*c+2] = q.z; xv[4*c+3] = q.w;
                sum += q.x + q.y + q.z + q.w;
            }
            const float mean = group8_fadd(sum) * (1.f/128.f);
            float vs = 0.f;
            #pragma unroll
            for (int c = 0; c < 16; ++c) { const float d = xv[c] - mean; xv[c] = d; vs = __fmaf_rn(d, d, vs); }
            const float inv = 1.f / __fsqrt_rn(group8_fadd(vs) * (1.f/128.f) + 1e-5f);
            const int j0 = s8*16;
            float* op = out + E_OFF + ((size_t)blk * K + e) * 128 + j0;
            #pragma unroll
            for (int c = 0; c < 4; ++c) {
                const float4 g4 = ((const float4*)(ge + j0))[c];
                const float4 b4 = ((const float4*)(be + j0))[c];
                float4 o;
                o.x = xv[4*c+0] * inv * g4.x + b4.x;
                o.y = xv[4*c+1] * inv * g4.y + b4.y;
                o.z = xv[4*c+2] * inv * g4.z + b4.z;
                o.w = xv[4*c+3] * inv * g4.w + b4.w;
                ((float4*)op)[c] = o;
            }
        }
    }
}

extern "C" void kernel_launch(void* const* d_in, const int* in_sizes, int n_in,
                              void* d_out, int out_size, void* d_ws, size_t ws_size,
                              hipStream_t stream) {
    const float* X    = (const float*)d_in[0];
    const float* mask = (const float*)d_in[1];
    // d_in[2] = Lvec (int32), unused
    const float* We   = (const float*)d_in[3];
    const float* Wn   = (const float*)d_in[4];
    const float* Wp   = (const float*)d_in[5];
    const float* bp   = (const float*)d_in[6];
    const float* gE   = (const float*)d_in[7];
    const float* bE   = (const float*)d_in[8];
    const float* gN   = (const float*)d_in[9];
    const float* bN   = (const float*)d_in[10];
    float* out = (float*)d_out;
    unsigned short* Wb = (unsigned short*)d_ws;                    // 106,496 B
    float4* ca4 = (float4*)((char*)d_ws + 106496);                 // 131,072 B
    unsigned* rtab = (unsigned*)((char*)d_ws + 106496 + 131072);   // 131,072 B

    hipLaunchKernelGGL(wb_prep_kernel,   dim3(13),   dim3(128), 0, stream, We, Wb);
    hipLaunchKernelGGL(rbf_tab_kernel,   dim3(16),   dim3(256), 0, stream, rtab);
    hipLaunchKernelGGL(node_bb_kernel,   dim3(8192), dim3(128), 0, stream, X, Wn, gN, bN, out, ca4);
    hipLaunchKernelGGL(topk_edge_kernel, dim3(8192), dim3(256), 0, stream,
                       X, mask, Wb, Wp, bp, gE, bE, ca4, rtab, out);
}

// Round 11
// 139.159 us; speedup vs baseline: 8.0999x; 1.1343x over previous
//
#include <hip/hip_runtime.h>
#include <hip/hip_bf16.h>
#include <math.h>

// Outputs are FLOAT32. B=8, L=1024, K=30, F=128 -> flat offsets (f32 elements):
#define V_OFF    ((size_t)0)
#define E_OFF    ((size_t)1048576)
#define EIDX_OFF ((size_t)32505856)
#define BB_OFF   ((size_t)32751616)

#define K 30
#define NRBF 16
#define AH   232          // A-half LDS row stride in bf16
#define SSTR 132          // padded S stride (f32)

typedef __attribute__((ext_vector_type(8))) short bf16x8;
typedef __attribute__((ext_vector_type(4))) float f32x4;

// atom indices: N=0, Ca=1, C=2, CB=3, O=4
__device__ __constant__ int c_pairA[24] = {0,2,4,3,1,1,1,1,0,0,0,3,3,4,0,2,4,3,2,4,3,2,4,2};
__device__ __constant__ int c_pairB[24] = {0,2,4,3,0,2,4,3,2,4,3,2,4,2,1,1,1,1,0,0,0,3,3,4};

// mu_k * 0.8 * sqrt(log2(e)) for exp2-folded RBF
__device__ __constant__ float c_muS[16] = {
    1.92179871f, 3.20299785f, 4.48419699f, 5.76539613f, 7.04659527f, 8.32779441f,
    9.60899355f, 10.89019269f, 12.17139183f, 13.45259097f, 14.73379011f, 16.01498925f,
    17.29618839f, 18.57738753f, 19.85858667f, 21.13978581f};

__device__ __forceinline__ unsigned short f2bu(float f) {   // RNE f32->bf16 bits (finite)
    unsigned x = __float_as_uint(f);
    return (unsigned short)((x + 0x7fffu + ((x >> 16) & 1u)) >> 16);
}

// ---- DPP wave-64 reductions (result broadcast via lane-63 readlane) ----
__device__ __forceinline__ unsigned wave_umin64(unsigned x) {
    unsigned t;
    t = __builtin_amdgcn_update_dpp(x, x, 0x111, 0xf, 0xf, false); x = min(x, t);
    t = __builtin_amdgcn_update_dpp(x, x, 0x112, 0xf, 0xf, false); x = min(x, t);
    t = __builtin_amdgcn_update_dpp(x, x, 0x114, 0xf, 0xf, false); x = min(x, t);
    t = __builtin_amdgcn_update_dpp(x, x, 0x118, 0xf, 0xf, false); x = min(x, t);
    t = __builtin_amdgcn_update_dpp(x, x, 0x142, 0xf, 0xf, false); x = min(x, t);
    t = __builtin_amdgcn_update_dpp(x, x, 0x143, 0xf, 0xf, false); x = min(x, t);
    return (unsigned)__builtin_amdgcn_readlane((int)x, 63);
}
__device__ __forceinline__ unsigned wave_umax64(unsigned x) {
    unsigned t;
    t = __builtin_amdgcn_update_dpp(x, x, 0x111, 0xf, 0xf, false); x = max(x, t);
    t = __builtin_amdgcn_update_dpp(x, x, 0x112, 0xf, 0xf, false); x = max(x, t);
    t = __builtin_amdgcn_update_dpp(x, x, 0x114, 0xf, 0xf, false); x = max(x, t);
    t = __builtin_amdgcn_update_dpp(x, x, 0x118, 0xf, 0xf, false); x = max(x, t);
    t = __builtin_amdgcn_update_dpp(x, x, 0x142, 0xf, 0xf, false); x = max(x, t);
    t = __builtin_amdgcn_update_dpp(x, x, 0x143, 0xf, 0xf, false); x = max(x, t);
    return (unsigned)__builtin_amdgcn_readlane((int)x, 63);
}
__device__ __forceinline__ float wave_fadd64(float x) {
    float t;
    t = __int_as_float(__builtin_amdgcn_update_dpp(0, __float_as_int(x), 0x111, 0xf, 0xf, true)); x += t;
    t = __int_as_float(__builtin_amdgcn_update_dpp(0, __float_as_int(x), 0x112, 0xf, 0xf, true)); x += t;
    t = __int_as_float(__builtin_amdgcn_update_dpp(0, __float_as_int(x), 0x114, 0xf, 0xf, true)); x += t;
    t = __int_as_float(__builtin_amdgcn_update_dpp(0, __float_as_int(x), 0x118, 0xf, 0xf, true)); x += t;
    t = __int_as_float(__builtin_amdgcn_update_dpp(0, __float_as_int(x), 0x142, 0xf, 0xf, true)); x += t;
    t = __int_as_float(__builtin_amdgcn_update_dpp(0, __float_as_int(x), 0x143, 0xf, 0xf, true)); x += t;
    return __int_as_float(__builtin_amdgcn_readlane(__float_as_int(x), 63));
}
__device__ __forceinline__ unsigned mbcnt64(unsigned long long m) {
    return __builtin_amdgcn_mbcnt_hi((unsigned)(m >> 32),
           __builtin_amdgcn_mbcnt_lo((unsigned)m, 0u));
}
// 8-lane butterfly sum (groups = lanes 8g..8g+7)
__device__ __forceinline__ float group8_fadd(float x) {
    float t;
    t = __int_as_float(__builtin_amdgcn_update_dpp(__float_as_int(x), __float_as_int(x), 0x0B1, 0xf, 0xf, false)); x += t;
    t = __int_as_float(__builtin_amdgcn_update_dpp(__float_as_int(x), __float_as_int(x), 0x04E, 0xf, 0xf, false)); x += t;
    x += __shfl_xor(x, 4, 64);
    return x;
}

__device__ __forceinline__ void norm_to(const float v[3], float o[3]) {
    float n = sqrtf(v[0]*v[0] + v[1]*v[1] + v[2]*v[2]);
    n = fmaxf(n, 1e-12f);
    o[0] = v[0]/n; o[1] = v[1]/n; o[2] = v[2]/n;
}
__device__ __forceinline__ void unit_diff(const float a[3], const float b[3], float o[3]) {
    float v[3] = {a[0]-b[0], a[1]-b[1], a[2]-b[2]};
    norm_to(v, o);
}
__device__ __forceinline__ void cross_unit(const float a[3], const float b[3], float o[3]) {
    float c[3] = {a[1]*b[2]-a[2]*b[1], a[2]*b[0]-a[0]*b[2], a[0]*b[1]-a[1]*b[0]};
    norm_to(c, o);
}

// ---------------- kernel 0a: We (400x128 f32) -> Wb fragment-major bf16 in ws ----------------
__global__ __launch_bounds__(128) void wb_prep_kernel(
    const float* __restrict__ We, unsigned short* __restrict__ Wb)
{
    const int s = blockIdx.x;          // 0..12
    const int j = threadIdx.x;         // 0..127
    unsigned* dst = (unsigned*)(Wb + ((size_t)(s*128 + j) << 5));
    #pragma unroll
    for (int m = 0; m < 16; ++m) {
        const int k0 = s*32 + 2*m;
        const unsigned lo = (k0   < 400) ? f2bu(We[(size_t)k0*128 + j])     : 0u;
        const unsigned hi = (k0+1 < 400) ? f2bu(We[(size_t)(k0+1)*128 + j]) : 0u;
        dst[m] = (hi << 16) | lo;
    }
}

// ---------------- kernel 0b: RBF lookup table: 4096 x 16 bf16 (d = idx*0.02) ----------------
__global__ __launch_bounds__(256) void rbf_tab_kernel(unsigned* __restrict__ tab)
{
    const int idx = blockIdx.x*256 + threadIdx.x;   // 0..4095
    const float t1 = (idx * 0.02f) * 0.96089935f;
    unsigned* dst = tab + ((size_t)idx << 3);
    #pragma unroll
    for (int m = 0; m < 8; ++m) {
        const float z0 = t1 - c_muS[2*m];
        const float z1 = t1 - c_muS[2*m+1];
        const float v0 = exp2f(-z0*z0);
        const float v1 = exp2f(-z1*z1);
        unsigned pk;
        asm("v_cvt_pk_bf16_f32 %0, %1, %2" : "=v"(pk) : "v"(v0), "v"(v1));
        dst[m] = pk;
    }
}

// ---------------- kernel 0c: pack Ca into float4 for coalesced phase-1 loads ----------------
__global__ __launch_bounds__(256) void ca_pack_kernel(
    const float* __restrict__ X, float4* __restrict__ ca4)
{
    const int idx = blockIdx.x*256 + threadIdx.x;   // 0..8191
    const float* p = X + (size_t)idx*15;
    ca4[idx] = make_float4(p[3], p[4], p[5], 0.f);
}

// ---------------- kernel 1: fused top-k + edges + node features + bb ----------------
__global__ __launch_bounds__(256, 8) void topk_edge_kernel(
    const float* __restrict__ X, const float* __restrict__ mask,
    const unsigned short* __restrict__ Wb, const float* __restrict__ Wp,
    const float* __restrict__ bp, const float* __restrict__ ge,
    const float* __restrict__ be, const float4* __restrict__ ca4,
    const unsigned* __restrict__ rtab,
    const float* __restrict__ Wn, const float* __restrict__ gn,
    const float* __restrict__ bn, float* __restrict__ out)
{
    const int blk = blockIdx.x;
    const int b = blk >> 10, i = blk & 1023;
    const int tid = threadIdx.x;
    const int w = tid >> 6, lane = tid & 63;

    __shared__ __align__(16) unsigned char uni_raw[K * SSTR * 4];  // 15840 B: surv / A-half / S union
    __shared__ float redf4[4];
    __shared__ unsigned redT[4];
    __shared__ int   scount;
    __shared__ float nbA[K][15];
    __shared__ int   nj[K];
    __shared__ float dnbv[K];
    __shared__ float angf[3];
    unsigned short* A_lds = (unsigned short*)uni_raw;
    float* S = (float*)uni_raw;
    unsigned long long* surv = (unsigned long long*)uni_raw;   // phase-1 only

    if (tid == 0) scount = 0;

    // ---- phase 1: masked distances (coalesced float4 Ca) ----
    const float4 me = ca4[(b << 10) + i];
    const float mi  = mask[(b << 10) + i];

    float dv_r[4], m2_r[4];
    float lmax = -1.f;
    #pragma unroll
    for (int m = 0; m < 4; ++m) {
        const int j = tid + (m << 8);
        const float4 cj = ca4[(b << 10) + j];
        const float dx = __fsub_rn(me.x, cj.x);
        const float dy = __fsub_rn(me.y, cj.y);
        const float dz = __fsub_rn(me.z, cj.z);
        // numpy association order: ((dx^2+dy^2)+dz^2)+1e-6
        const float ss = __fadd_rn(__fadd_rn(__fmul_rn(dx,dx), __fmul_rn(dy,dy)), __fmul_rn(dz,dz));
        const float dist = __fsqrt_rn(__fadd_rn(ss, 1e-6f));
        const float m2 = __fmul_rn(mi, mask[(b << 10) + j]);
        const float Dv = __fmul_rn(m2, dist);
        dv_r[m] = Dv; m2_r[m] = m2;
        lmax = fmaxf(lmax, Dv);
    }
    const float wmax = __uint_as_float(wave_umax64(__float_as_uint(lmax)));
    if (lane == 0) redf4[w] = wmax;
    __syncthreads();           // also covers scount init
    const float Dmax = fmaxf(fmaxf(redf4[0], redf4[1]), fmaxf(redf4[2], redf4[3]));

    unsigned va[4];
    #pragma unroll
    for (int m = 0; m < 4; ++m)
        va[m] = __float_as_uint(__fadd_rn(dv_r[m], __fmul_rn(__fsub_rn(1.f, m2_r[m]), Dmax)));

    // ---- Step A: per-wave value-only top-8 -> threshold Tw ----
    {
        unsigned vb0 = va[0], vb1 = va[1], vb2 = va[2], vb3 = va[3];
        unsigned v = 0;
        #pragma unroll
        for (int k = 0; k < 8; ++k) {
            const unsigned head = min(min(vb0, vb1), min(vb2, vb3));
            v = wave_umin64(head);
            vb0 = (vb0 == v) ? 0xffffffffu : vb0;
            vb1 = (vb1 == v) ? 0xffffffffu : vb1;
            vb2 = (vb2 == v) ? 0xffffffffu : vb2;
            vb3 = (vb3 == v) ? 0xffffffffu : vb3;
        }
        if (lane == 0) redT[w] = v;
    }
    __syncthreads();
    // T = max of wave thresholds: >= 32 candidates <= T, so all top-30 survive.
    const unsigned T = max(max(redT[0], redT[1]), max(redT[2], redT[3]));

    // ---- Step B: compact survivors (value<<32|index) into LDS ----
    {
        unsigned long long mm0 = __ballot(va[0] <= T);
        unsigned long long mm1 = __ballot(va[1] <= T);
        unsigned long long mm2 = __ballot(va[2] <= T);
        unsigned long long mm3 = __ballot(va[3] <= T);
        const unsigned c0 = __popcll(mm0), c1 = __popcll(mm1);
        const unsigned c2 = __popcll(mm2), c3 = __popcll(mm3);
        int old = 0;
        if (lane == 0) old = atomicAdd(&scount, (int)(c0 + c1 + c2 + c3));
        unsigned base = (unsigned)__builtin_amdgcn_readfirstlane(old);
        if (va[0] <= T) surv[base + mbcnt64(mm0)] = ((unsigned long long)va[0] << 32) | (unsigned)tid;
        base += c0;
        if (va[1] <= T) surv[base + mbcnt64(mm1)] = ((unsigned long long)va[1] << 32) | (unsigned)(tid + 256);
        base += c1;
        if (va[2] <= T) surv[base + mbcnt64(mm2)] = ((unsigned long long)va[2] << 32) | (unsigned)(tid + 512);
        base += c2;
        if (va[3] <= T) surv[base + mbcnt64(mm3)] = ((unsigned long long)va[3] << 32) | (unsigned)(tid + 768);
    }
    __syncthreads();
    const int N = scount;

    // ---- Step C: distributed exact rank selection (keys unique -> ranks a permutation) ----
    for (int base = 0; base < N; base += 256) {
        const int t = base + tid;
        if (t < N) {
            const unsigned long long mykey = surv[t];
            int rank = 0;
            #pragma unroll 4
            for (int u = 0; u < N; ++u) rank += (surv[u] < mykey) ? 1 : 0;
            if (rank < K) {
                const int j = (int)(mykey & 0xffffffffu);
                nj[rank] = j;
                dnbv[rank] = __uint_as_float((unsigned)(mykey >> 32));
                out[EIDX_OFF + (size_t)blk * K + rank] = (float)j;
            }
        }
    }
    __syncthreads();

    // ---- fetch neighbor atoms ----
    for (int t = tid; t < K*15; t += 256) {
        const int e = t / 15, r = t - e*15;
        nbA[e][r] = X[((size_t)(b << 10) + nj[e])*15 + r];
    }
    __syncthreads();

    const float* sa = X + (size_t)blk * 15;
    f32x4 acc00 = {0,0,0,0}, acc01 = {0,0,0,0}, acc10 = {0,0,0,0}, acc11 = {0,0,0,0};
    const int ar = lane & 15;
    const int kg = (lane >> 4) * 8;
    const unsigned short* a_base = A_lds + ar*AH + kg;
    const unsigned short* a_base1 = a_base + 16*AH;
    const unsigned short* b_base = Wb + ((size_t)(w*32 + ar) << 5) + kg;

    // ================= PASS 1: g in [0,12), k-global [0,192) =================
    for (int t = tid; t < K*12; t += 256) {
        const int e = t / 12, g = t - e*12;
        float d;
        if (g == 0) d = dnbv[e];
        else {
            const int p = g - 1;
            const int aA = c_pairA[p], aB = c_pairB[p];
            const float dx = sa[aA*3+0] - nbA[e][aB*3+0];
            const float dy = sa[aA*3+1] - nbA[e][aB*3+1];
            const float dz = sa[aA*3+2] - nbA[e][aB*3+2];
            d = sqrtf(dx*dx + dy*dy + dz*dz + 1e-6f);
        }
        int idx = (int)__fmaf_rn(d, 50.f, 0.5f);
        idx = min(idx, 4095);
        const uint4* src = (const uint4*)(rtab + ((size_t)idx << 3));
        uint4* dst = (uint4*)(A_lds + e*AH + g*NRBF);
        dst[0] = src[0]; dst[1] = src[1];
    }
    __syncthreads();
    #pragma unroll
    for (int s = 0; s < 6; ++s) {
        const bf16x8 a0 = *reinterpret_cast<const bf16x8*>(a_base + s*32);
        const bf16x8 a1 = *reinterpret_cast<const bf16x8*>(a_base1 + s*32);
        const bf16x8 b0 = *reinterpret_cast<const bf16x8*>(b_base + (size_t)s*4096);
        const bf16x8 b1 = *reinterpret_cast<const bf16x8*>(b_base + (size_t)s*4096 + 512);
        acc00 = __builtin_amdgcn_mfma_f32_16x16x32_bf16(a0, b0, acc00, 0, 0, 0);
        acc01 = __builtin_amdgcn_mfma_f32_16x16x32_bf16(a0, b1, acc01, 0, 0, 0);
        acc10 = __builtin_amdgcn_mfma_f32_16x16x32_bf16(a1, b0, acc10, 0, 0, 0);
        acc11 = __builtin_amdgcn_mfma_f32_16x16x32_bf16(a1, b1, acc11, 0, 0, 0);
    }
    __syncthreads();   // pass-1 A reads complete

    // ================= PASS 2: g in [12,25), k-global [192,400)+pad =================
    for (int t = tid; t < K*13; t += 256) {
        const int e = t / 13, gg = t - e*13;
        const int p = 11 + gg;
        const int aA = c_pairA[p], aB = c_pairB[p];
        const float dx = sa[aA*3+0] - nbA[e][aB*3+0];
        const float dy = sa[aA*3+1] - nbA[e][aB*3+1];
        const float dz = sa[aA*3+2] - nbA[e][aB*3+2];
        const float d = sqrtf(dx*dx + dy*dy + dz*dz + 1e-6f);
        int idx = (int)__fmaf_rn(d, 50.f, 0.5f);
        idx = min(idx, 4095);
        const uint4* src = (const uint4*)(rtab + ((size_t)idx << 3));
        uint4* dst = (uint4*)(A_lds + e*AH + gg*NRBF);
        dst[0] = src[0]; dst[1] = src[1];
    }
    // zero k-local pad [208,224) for data rows 0..29
    for (int t = tid; t < K*8; t += 256) {
        const int e = t >> 3, c = t & 7;
        ((unsigned*)(A_lds + e*AH + 208))[c] = 0u;
    }
    __syncthreads();
    #pragma unroll
    for (int s = 0; s < 7; ++s) {
        const bf16x8 a0 = *reinterpret_cast<const bf16x8*>(a_base + s*32);
        const bf16x8 a1 = *reinterpret_cast<const bf16x8*>(a_base1 + s*32);
        const bf16x8 b0 = *reinterpret_cast<const bf16x8*>(b_base + (size_t)(6+s)*4096);
        const bf16x8 b1 = *reinterpret_cast<const bf16x8*>(b_base + (size_t)(6+s)*4096 + 512);
        acc00 = __builtin_amdgcn_mfma_f32_16x16x32_bf16(a0, b0, acc00, 0, 0, 0);
        acc01 = __builtin_amdgcn_mfma_f32_16x16x32_bf16(a0, b1, acc01, 0, 0, 0);
        acc10 = __builtin_amdgcn_mfma_f32_16x16x32_bf16(a1, b0, acc10, 0, 0, 0);
        acc11 = __builtin_amdgcn_mfma_f32_16x16x32_bf16(a1, b1, acc11, 0, 0, 0);
    }
    __syncthreads();   // pass-2 A reads complete; union region becomes S

    {
        // C layout (m89): col = lane&15, row = (lane>>4)*4 + reg
        const int crow = (lane >> 4) * 4;
        const int ccol = w*32 + (lane & 15);
        #pragma unroll
        for (int r = 0; r < 4; ++r) {
            const int r0 = crow + r;
            if (r0 < K) { S[r0*SSTR + ccol] = acc00[r]; S[r0*SSTR + ccol + 16] = acc01[r]; }
            const int r1 = 16 + crow + r;
            if (r1 < K) { S[r1*SSTR + ccol] = acc10[r]; S[r1*SSTR + ccol + 16] = acc11[r]; }
        }
    }
    __syncthreads();

    // ---- positional embedding + bias (float4 items: 30 edges x 32 quads) ----
    #pragma unroll
    for (int n = 0; n < 4; ++n) {
        const int item = tid + (n << 8);
        if (item < 960) {
            const int e = item >> 5, q = item & 31;
            int off = i - nj[e] + 32;
            off = off < 0 ? 0 : (off > 64 ? 64 : off);
            const float4 wp = ((const float4*)(Wp + (size_t)off*128))[q];
            const float4 bq = ((const float4*)bp)[q];
            float4* sp = (float4*)(S + e*SSTR) + q;
            float4 sv = *sp;
            sv.x += wp.x + bq.x; sv.y += wp.y + bq.y;
            sv.z += wp.z + bq.z; sv.w += wp.w + bq.w;
            *sp = sv;
        }
    }
    __syncthreads();

    // ---- per-edge LayerNorm: one thread per (edge, 16-elem strip) ----
    {
        const int e = tid >> 3, s8 = tid & 7;
        if (e < K) {
            const float* row = S + e*SSTR + s8*16;
            float xv[16];
            float sum = 0.f;
            #pragma unroll
            for (int c = 0; c < 4; ++c) {
                const float4 q = ((const float4*)row)[c];
                xv[4*c+0] = q.x; xv[4*c+1] = q.y; xv[4*c+2] = q.z; xv[4*c+3] = q.w;
                sum += q.x + q.y + q.z + q.w;
            }
            const float mean = group8_fadd(sum) * (1.f/128.f);
            float vs = 0.f;
            #pragma unroll
            for (int c = 0; c < 16; ++c) { const float d = xv[c] - mean; xv[c] = d; vs = __fmaf_rn(d, d, vs); }
            const float inv = 1.f / __fsqrt_rn(group8_fadd(vs) * (1.f/128.f) + 1e-5f);
            const int j0 = s8*16;
            float* op = out + E_OFF + ((size_t)blk * K + e) * 128 + j0;
            #pragma unroll
            for (int c = 0; c < 4; ++c) {
                const float4 g4 = ((const float4*)(ge + j0))[c];
                const float4 b4 = ((const float4*)(be + j0))[c];
                float4 o;
                o.x = xv[4*c+0] * inv * g4.x + b4.x;
                o.y = xv[4*c+1] * inv * g4.y + b4.y;
                o.z = xv[4*c+2] * inv * g4.z + b4.z;
                o.w = xv[4*c+3] * inv * g4.w + b4.w;
                ((float4*)op)[c] = o;
            }
        }
    }

    // ================= fused node features V + backbone bb =================
    if (tid < 3) {
        const int m = 3*i + tid;
        float dang = 0.f;
        if (m >= 1 && m <= 3*1024 - 3) {
            const int t = m - 1;
            float P[4][3];
            #pragma unroll
            for (int q = 0; q < 4; ++q) {
                const int s = t + q;
                const int ri = s / 3, ai = s - 3*ri;
                const float* p = X + (((size_t)b * 1024 + ri) * 5 + ai) * 3;
                P[q][0] = p[0]; P[q][1] = p[1]; P[q][2] = p[2];
            }
            float u2v[3], u1v[3], u0v[3];
            unit_diff(P[1], P[0], u2v);
            unit_diff(P[2], P[1], u1v);
            unit_diff(P[3], P[2], u0v);
            float n2v[3], n1v[3];
            cross_unit(u2v, u1v, n2v);
            cross_unit(u1v, u0v, n1v);
            float cosD = n2v[0]*n1v[0] + n2v[1]*n1v[1] + n2v[2]*n1v[2];
            cosD = fminf(fmaxf(cosD, -1.f + 1e-7f), 1.f - 1e-7f);
            float sg = u2v[0]*n1v[0] + u2v[1]*n1v[1] + u2v[2]*n1v[2];
            float s = (sg > 0.f) ? 1.f : ((sg < 0.f) ? -1.f : 0.f);
            dang = s * acosf(cosD);
        }
        angf[tid] = dang;
    }
    if (tid == 3) {
        float Nx=sa[0],  Ny=sa[1],  Nz=sa[2];
        float Cax=sa[3], Cay=sa[4], Caz=sa[5];
        float Cx=sa[6],  Cy=sa[7],  Cz=sa[8];
        float v1[3] = {Cx-Cax, Cy-Cay, Cz-Caz};
        float v2[3] = {Nx-Cax, Ny-Cay, Nz-Caz};
        float e1[3]; norm_to(v1, e1);
        float dd = e1[0]*v2[0] + e1[1]*v2[1] + e1[2]*v2[2];
        float u2[3] = {v2[0]-e1[0]*dd, v2[1]-e1[1]*dd, v2[2]-e1[2]*dd};
        float e2[3]; norm_to(u2, e2);
        float e3[3] = {e1[1]*e2[2]-e1[2]*e2[1], e1[2]*e2[0]-e1[0]*e2[2], e1[0]*e2[1]-e1[1]*e2[0]};
        float* bb = out + BB_OFF + (size_t)blk * 16;
        bb[0]=e1[0]; bb[1]=e1[1]; bb[2]=e1[2];  bb[3]=Cax;
        bb[4]=e2[0]; bb[5]=e2[1]; bb[6]=e2[2];  bb[7]=Cay;
        bb[8]=e3[0]; bb[9]=e3[1]; bb[10]=e3[2]; bb[11]=Caz;
        bb[12]=0.f; bb[13]=0.f; bb[14]=0.f; bb[15]=0.f;
    }
    __syncthreads();
    float xV = 0.f;
    if (tid < 128) {
        const float a0 = angf[0], a1 = angf[1], a2 = angf[2];
        const float feat[6] = {cosf(a0), cosf(a1), cosf(a2), sinf(a0), sinf(a1), sinf(a2)};
        #pragma unroll
        for (int f = 0; f < 6; ++f) xV += feat[f] * Wn[f*128 + tid];
        const float s = wave_fadd64(xV);
        if (lane == 0) redf4[w] = s;
    }
    __syncthreads();
    if (tid < 128) {
        const float mean = (redf4[0] + redf4[1]) * (1.f/128.f);
        const float xm = xV - mean;
        const float vsum = wave_fadd64(xm*xm);
        if (lane == 0) redT[w] = __float_as_uint(vsum);
        __builtin_amdgcn_s_barrier();   // waves 0,1 only — both reach it
        const float var = (__uint_as_float(redT[0]) + __uint_as_float(redT[1])) * (1.f/128.f);
        out[V_OFF + (size_t)blk * 128 + tid] = xm / __fsqrt_rn(var + 1e-5f) * gn[tid] + bn[tid];
    }
}

extern "C" void kernel_launch(void* const* d_in, const int* in_sizes, int n_in,
                              void* d_out, int out_size, void* d_ws, size_t ws_size,
                              hipStream_t stream) {
    const float* X    = (const float*)d_in[0];
    const float* mask = (const float*)d_in[1];
    // d_in[2] = Lvec (int32), unused
    const float* We   = (const float*)d_in[3];
    const float* Wn   = (const float*)d_in[4];
    const float* Wp   = (const float*)d_in[5];
    const float* bp   = (const float*)d_in[6];
    const float* gE   = (const float*)d_in[7];
    const float* bE   = (const float*)d_in[8];
    const float* gN   = (const float*)d_in[9];
    const float* bN   = (const float*)d_in[10];
    float* out = (float*)d_out;
    unsigned short* Wb = (unsigned short*)d_ws;                    // 106,496 B
    float4* ca4 = (float4*)((char*)d_ws + 106496);                 // 131,072 B
    unsigned* rtab = (unsigned*)((char*)d_ws + 106496 + 131072);   // 131,072 B

    hipLaunchKernelGGL(wb_prep_kernel,   dim3(13),   dim3(128), 0, stream, We, Wb);
    hipLaunchKernelGGL(rbf_tab_kernel,   dim3(16),   dim3(256), 0, stream, rtab);
    hipLaunchKernelGGL(ca_pack_kernel,   dim3(32),   dim3(256), 0, stream, X, ca4);
    hipLaunchKernelGGL(topk_edge_kernel, dim3(8192), dim3(256), 0, stream,
                       X, mask, Wb, Wp, bp, gE, bE, ca4, rtab, Wn, gN, bN, out);
}